// Round 1
// 578.509 us; speedup vs baseline: 1.1997x; 1.1997x over previous
//
#include <hip/hip_runtime.h>
#include <hip/hip_fp16.h>
#include <math.h>

// Problem constants
#define Bb 32
#define Nn 1024
#define DIMc 512
#define Hh 8
#define DHd 64
#define GK 512          // K for both projection GEMMs

typedef __attribute__((ext_vector_type(8))) short short8;   // 8 bf16 (4 VGPRs)
typedef __attribute__((ext_vector_type(4))) float floatx4;  // MFMA 16x16 acc

#define MFMA __builtin_amdgcn_mfma_f32_16x16x32_bf16

#if __has_builtin(__builtin_amdgcn_exp2f)
#define EXP2(x) __builtin_amdgcn_exp2f(x)
#else
#define EXP2(x) __expf((x) * 0.6931471805599453f)
#endif

__device__ __forceinline__ unsigned short bf16_rtn(float f) {
    unsigned int u = __float_as_uint(f);
    u += 0x7FFFu + ((u >> 16) & 1u);     // round-to-nearest-even
    return (unsigned short)(u >> 16);
}
__device__ __forceinline__ float bf16_to_f32(unsigned short h) {
    return __uint_as_float(((unsigned int)h) << 16);
}
// Truncation split: f == hi + lo exactly in fp32 (Dekker-style); lo then
// truncated to bf16 (residual of residual ~2^-16 rel -- below noise floor).
__device__ __forceinline__ void split_trunc(float f, unsigned short& hi, unsigned short& lo) {
    unsigned int u = __float_as_uint(f) & 0xFFFF0000u;
    hi = (unsigned short)(u >> 16);
    float rest = f - __uint_as_float(u);
    lo = (unsigned short)(__float_as_uint(rest) >> 16);
}
// pack 2 fp32 -> 2 bf16 in one dword (lo -> bits 0..15, hi -> bits 16..31)
__device__ __forceinline__ int cvt_pk_bf16(float lo, float hi) {
    int r;
    asm("v_cvt_pk_bf16_f32 %0, %1, %2" : "=v"(r) : "v"(lo), "v"(hi));
    return r;
}

// ---------------------------------------------------------------------------
// Prep 1: transpose + split fp32 weight [K][N] -> hi/lo bf16 [N][K]
// ---------------------------------------------------------------------------
__global__ __launch_bounds__(256) void transpose_split_kernel(
    const float* __restrict__ src, int K, int N,
    unsigned short* __restrict__ dh, unsigned short* __restrict__ dl)
{
    __shared__ float T[32][33];
    const int tid = threadIdx.x;
    const int c = tid & 31, r0 = tid >> 5;
    const int nb = blockIdx.x * 32, kb = blockIdx.y * 32;
    #pragma unroll
    for (int i = 0; i < 4; ++i)
        T[r0 + i * 8][c] = src[(size_t)(kb + r0 + i * 8) * N + nb + c];
    __syncthreads();
    #pragma unroll
    for (int i = 0; i < 4; ++i) {
        int n = r0 + i * 8;
        unsigned short hi, lo;
        split_trunc(T[c][n], hi, lo);
        size_t off = (size_t)(nb + n) * K + kb + c;
        dh[off] = hi;
        dl[off] = lo;
    }
}

// ---------------------------------------------------------------------------
// Prep 2: decay fp32 -> fp16 (post-softmax multiplier; fp16 rel err ~5e-4)
// ---------------------------------------------------------------------------
__global__ __launch_bounds__(256) void decay_to_half_kernel(
    const float* __restrict__ D, unsigned short* __restrict__ D16)
{
    size_t i = ((size_t)blockIdx.x * 256 + threadIdx.x) * 4;
    float4 v = *(const float4*)(D + i);
    ushort4 o;
    o.x = __half_as_ushort(__float2half(v.x));
    o.y = __half_as_ushort(__float2half(v.y));
    o.z = __half_as_ushort(__float2half(v.z));
    o.w = __half_as_ushort(__float2half(v.w));
    *(ushort4*)(D16 + i) = o;
}

// ---------------------------------------------------------------------------
// GEMM1 (MFMA, 3-term split): qkv = x @ W_qkv
// Q epilogue folds SCALE * log2(e) so attention exps are raw v_exp_f32.
// ---------------------------------------------------------------------------
__global__ __launch_bounds__(256) void gemm_qkv_mfma(
    const float* __restrict__ X,
    const unsigned short* __restrict__ Wh, const unsigned short* __restrict__ Wl,
    unsigned short* __restrict__ Qh, unsigned short* __restrict__ Ql,
    unsigned short* __restrict__ Kh, unsigned short* __restrict__ Kl,
    unsigned short* __restrict__ Vt)
{
    __shared__ union {
        struct { unsigned short Ah[4096], Al[4096], Bh[4096], Bl[4096]; } s;
        unsigned short bounce[128][136];   // V-transpose bounce (epilogue only)
    } u;

    const int tid  = threadIdx.x;
    const int w    = tid >> 6;
    const int lane = tid & 63;
    const int quad = lane >> 4;
    const int l16  = lane & 15;
    const int n0 = blockIdx.x * 128;
    const int m0 = blockIdx.y * 128;
    const int wm = w >> 1, wn = w & 1;

    floatx4 acc[4][4];
    #pragma unroll
    for (int im = 0; im < 4; ++im)
        #pragma unroll
        for (int in = 0; in < 4; ++in)
            acc[im][in] = (floatx4){0.f, 0.f, 0.f, 0.f};

    for (int k0 = 0; k0 < GK; k0 += 32) {
        float4 av[2][2];
        short8 wbh[2], wbl[2];
        #pragma unroll
        for (int i = 0; i < 2; ++i) {
            const int row = i * 64 + w * 16 + l16;
            const float* ap = X + (size_t)(m0 + row) * GK + k0 + quad * 8;
            av[i][0] = *(const float4*)ap;
            av[i][1] = *(const float4*)(ap + 4);
            const size_t boff = (size_t)(n0 + row) * GK + k0 + quad * 8;
            wbh[i] = *(const short8*)(Wh + boff);
            wbl[i] = *(const short8*)(Wl + boff);
        }
        __syncthreads();
        #pragma unroll
        for (int i = 0; i < 2; ++i) {
            float fv[8] = {av[i][0].x, av[i][0].y, av[i][0].z, av[i][0].w,
                           av[i][1].x, av[i][1].y, av[i][1].z, av[i][1].w};
            short8 hi, lo;
            #pragma unroll
            for (int e = 0; e < 8; ++e) {
                unsigned short h_, l_;
                split_trunc(fv[e], h_, l_);
                hi[e] = (short)h_;
                lo[e] = (short)l_;
            }
            const int ci = ((i * 4 + w) * 4 + quad) * 16 + l16;
            *(short8*)&u.s.Ah[ci * 8] = hi;
            *(short8*)&u.s.Al[ci * 8] = lo;
            *(short8*)&u.s.Bh[ci * 8] = wbh[i];
            *(short8*)&u.s.Bl[ci * 8] = wbl[i];
        }
        __syncthreads();

        short8 fah[4], fal[4], fbh[4], fbl[4];
        #pragma unroll
        for (int t = 0; t < 4; ++t) {
            const int ca = ((wm * 4 + t) * 4 + quad) * 16 + l16;
            fah[t] = *(const short8*)&u.s.Ah[ca * 8];
            fal[t] = *(const short8*)&u.s.Al[ca * 8];
            const int cb = ((wn * 4 + t) * 4 + quad) * 16 + l16;
            fbh[t] = *(const short8*)&u.s.Bh[cb * 8];
            fbl[t] = *(const short8*)&u.s.Bl[cb * 8];
        }
        #pragma unroll
        for (int im = 0; im < 4; ++im)
            #pragma unroll
            for (int in = 0; in < 4; ++in) {
                floatx4 a = acc[im][in];
                a = MFMA(fah[im], fbh[in], a, 0, 0, 0);
                a = MFMA(fal[im], fbh[in], a, 0, 0, 0);
                a = MFMA(fah[im], fbl[in], a, 0, 0, 0);
                acc[im][in] = a;
            }
    }

    // ---- epilogue ----
    const int which = n0 >> 9;       // 0=q 1=k 2=v (128-tiles never straddle)
    const int b    = m0 >> 10;
    const int tokb = m0 & 1023;
    if (which < 2) {
        unsigned short* HI = which ? Kh : Qh;
        unsigned short* LO = which ? Kl : Ql;
        // Q: fold SCALE * log2(e) = 0.125 * 1.4426950408889634
        const float sc = which ? 1.0f : 0.18033688011112042f;
        #pragma unroll
        for (int im = 0; im < 4; ++im) {
            const int tok = tokb + wm * 64 + im * 16 + quad * 4;
            #pragma unroll
            for (int in = 0; in < 4; ++in) {
                const int ncol = n0 + wn * 64 + in * 16 + l16;
                const int h = (ncol & 511) >> 6, d = ncol & 63;
                const size_t base = ((size_t)(b * Hh + h) * Nn + tok) * DHd + d;
                #pragma unroll
                for (int r = 0; r < 4; ++r) {
                    unsigned short hi, lo;
                    split_trunc(acc[im][in][r] * sc, hi, lo);
                    HI[base + (size_t)r * DHd] = hi;
                    LO[base + (size_t)r * DHd] = lo;
                }
            }
        }
    } else {
        // V: bf16 + transpose through LDS bounce -> Vt [bh][64][1024]
        __syncthreads();
        #pragma unroll
        for (int im = 0; im < 4; ++im)
            #pragma unroll
            for (int in = 0; in < 4; ++in)
                #pragma unroll
                for (int r = 0; r < 4; ++r)
                    u.bounce[wm * 64 + im * 16 + quad * 4 + r][wn * 64 + in * 16 + l16] =
                        bf16_rtn(acc[im][in][r]);
        __syncthreads();
        const int c = tid >> 1, tq = (tid & 1) * 64;
        const int h = ((n0 + c) & 511) >> 6, d = c & 63;
        unsigned short* vbase = Vt + ((size_t)(b * Hh + h) * DHd + d) * Nn + tokb;
        #pragma unroll
        for (int uu = 0; uu < 8; ++uu) {
            short8 v8;
            #pragma unroll
            for (int e = 0; e < 8; ++e)
                v8[e] = (short)u.bounce[tq + uu * 8 + e][c];
            *(short8*)&vbase[tq + uu * 8] = v8;
        }
    }
}

// ---------------------------------------------------------------------------
// MFMA flash attention, restructured:
//  * QK^T computed SWAPPED (mfma(K, Q)) so each lane owns one q-row (q = l16):
//    row max/sum = in-lane ops + 2 shuffles (vs 32 shuffles before).
//  * K staged into LDS with PERMUTED rows so the lane's 8 score values land
//    exactly at PV A-fragment slots k = quad*8 + e -> P transpose is 4
//    v_cvt_pk_bf16_f32 in-register, no LDS round-trip (Ps deleted).
//  * exps are raw v_exp_f32 (log2(e) folded into Q scale in GEMM1).
//  * T13 defer-max (THR=8 in log2 domain) skips rescale on most tiles.
//  * T14 async-STAGE: next K/V tile prefetched into regs right after the
//    barrier; global latency hides under QK+softmax+PV.
// ---------------------------------------------------------------------------
__global__ __launch_bounds__(256) void attn_mfma_kernel(
    const unsigned short* __restrict__ Qh, const unsigned short* __restrict__ Ql,
    const unsigned short* __restrict__ Kh, const unsigned short* __restrict__ Kl,
    const unsigned short* __restrict__ Vt, const unsigned short* __restrict__ D16,
    unsigned short* __restrict__ AOh, unsigned short* __restrict__ AOl)
{
    __shared__ unsigned short Khs[32][72];   // [permuted j][d]
    __shared__ unsigned short Kls[32][72];
    __shared__ unsigned short Vts[64][40];   // [d][j]

    const int tid  = threadIdx.x;
    const int wave = tid >> 6;
    const int lane = tid & 63;
    const int quad = lane >> 4;
    const int l16  = lane & 15;
    const int bh   = blockIdx.x;
    const int b    = bh >> 3, h = bh & 7;
    const int i0   = blockIdx.y * 64;
    const int iw   = i0 + wave * 16;

    // Q fragments (serve as MFMA B operand: col = l16 = q-row, k = quad*8+e = d)
    const size_t qoff = ((size_t)bh * Nn + iw + l16) * DHd + quad * 8;
    const short8 qh0 = *(const short8*)(Qh + qoff);
    const short8 qh1 = *(const short8*)(Qh + qoff + 32);
    const short8 ql0 = *(const short8*)(Ql + qoff);
    const short8 ql1 = *(const short8*)(Ql + qoff + 32);

    floatx4 o_acc[4];
    #pragma unroll
    for (int nt = 0; nt < 4; ++nt) o_acc[nt] = (floatx4){0.f, 0.f, 0.f, 0.f};
    float m = -INFINITY;      // per-lane: row q = l16 (replicated across quads)
    float l = 0.f;

    // staging indices; K rows permuted so that frag row (nh*16 + l16) holds
    // K row j = quad*8 + nh*4 + r  =>  prow(sj) = ((sj>>2)&1)*16+(sj>>3)*4+(sj&3)
    const int sj  = tid >> 3, sc2 = (tid & 7) * 8;       // K tiles: 32 x 64
    const int prow = ((sj >> 2) & 1) * 16 + ((sj >> 3) << 2) + (sj & 3);
    const int vd  = tid >> 2, vj8 = (tid & 3) * 8;       // Vt tile: 64 x 32
    const size_t kbase  = (size_t)bh * Nn * DHd;
    const size_t vtbase = (size_t)bh * DHd * Nn;
    // decay: this lane needs row q = iw+l16, cols j0 + quad*8 .. +7 (one 16B load)
    const unsigned short* Dp = D16 + ((size_t)h * Nn + iw + l16) * Nn + quad * 8;

    // T14 prologue: prefetch tile 0 into regs
    short8 pk_h = *(const short8*)&Kh[kbase + (size_t)sj * DHd + sc2];
    short8 pk_l = *(const short8*)&Kl[kbase + (size_t)sj * DHd + sc2];
    short8 pk_v = *(const short8*)&Vt[vtbase + (size_t)vd * Nn + vj8];

    for (int j0 = 0; j0 < Nn; j0 += 32) {
        const short8 dc = *(const short8*)(Dp + j0);     // 8 fp16 decay values
        __syncthreads();
        *(short8*)&Khs[prow][sc2] = pk_h;
        *(short8*)&Kls[prow][sc2] = pk_l;
        *(short8*)&Vts[vd][vj8]   = pk_v;
        __syncthreads();
        {   // T14: issue next tile's loads now; latency hides under compute
            const int jn = (j0 + 32) & (Nn - 1);
            pk_h = *(const short8*)&Kh[kbase + (size_t)(jn + sj) * DHd + sc2];
            pk_l = *(const short8*)&Kl[kbase + (size_t)(jn + sj) * DHd + sc2];
            pk_v = *(const short8*)&Vt[vtbase + (size_t)vd * Nn + jn + vj8];
        }

        // QK^T swapped: A = K (row = j), B = Q (col = q). 3-term split.
        floatx4 sacc[2];
        #pragma unroll
        for (int nh = 0; nh < 2; ++nh) {
            const int kr = nh * 16 + l16;
            short8 kh0 = *(const short8*)&Khs[kr][quad * 8];
            short8 kh1 = *(const short8*)&Khs[kr][32 + quad * 8];
            short8 kl0 = *(const short8*)&Kls[kr][quad * 8];
            short8 kl1 = *(const short8*)&Kls[kr][32 + quad * 8];
            floatx4 a = (floatx4){0.f, 0.f, 0.f, 0.f};
            a = MFMA(kh0, qh0, a, 0, 0, 0);
            a = MFMA(kh1, qh1, a, 0, 0, 0);
            a = MFMA(kl0, qh0, a, 0, 0, 0);
            a = MFMA(kl1, qh1, a, 0, 0, 0);
            a = MFMA(kh0, ql0, a, 0, 0, 0);
            a = MFMA(kh1, ql1, a, 0, 0, 0);
            sacc[nh] = a;
        }
        // lane now holds S[q=l16][j0 + quad*8 + nh*4 + r]  (log2 domain)

        // row max: 7 in-lane + 2 cross-quad shuffles
        float t = fmaxf(fmaxf(fmaxf(sacc[0][0], sacc[0][1]), fmaxf(sacc[0][2], sacc[0][3])),
                        fmaxf(fmaxf(sacc[1][0], sacc[1][1]), fmaxf(sacc[1][2], sacc[1][3])));
        t = fmaxf(t, __shfl_xor(t, 16));
        t = fmaxf(t, __shfl_xor(t, 32));

        // T13 defer-max: skip rescale while p stays <= 2^8
        if (!__all(t <= m + 8.0f)) {
            const float nm = fmaxf(m, t);
            const float fac = EXP2(m - nm);
            m = nm;
            l *= fac;
            float fr[4];
            #pragma unroll
            for (int r = 0; r < 4; ++r) fr[r] = __shfl(fac, quad * 4 + r);
            #pragma unroll
            for (int nt = 0; nt < 4; ++nt) {
                floatx4 t4 = o_acc[nt];
                t4[0] *= fr[0]; t4[1] *= fr[1]; t4[2] *= fr[2]; t4[3] *= fr[3];
                o_acc[nt] = t4;
            }
        }

        float p[8];
        #pragma unroll
        for (int e = 0; e < 4; ++e) p[e]     = EXP2(sacc[0][e] - m);
        #pragma unroll
        for (int e = 0; e < 4; ++e) p[4 + e] = EXP2(sacc[1][e] - m);
        float ps = ((p[0] + p[1]) + (p[2] + p[3])) + ((p[4] + p[5]) + (p[6] + p[7]));
        ps += __shfl_xor(ps, 16);
        ps += __shfl_xor(ps, 32);
        l += ps;                               // denom WITHOUT decay

        // P * decay -> bf16 A-fragment, fully in-register (no LDS, no shuffles)
        union { int i4[4]; short8 s8; } pfu;
        #pragma unroll
        for (int e = 0; e < 4; ++e) {
            const float d0 = __half2float(__ushort_as_half((unsigned short)dc[2 * e]));
            const float d1 = __half2float(__ushort_as_half((unsigned short)dc[2 * e + 1]));
            pfu.i4[e] = cvt_pk_bf16(p[2 * e] * d0, p[2 * e + 1] * d1);
        }
        #pragma unroll
        for (int nt = 0; nt < 4; ++nt) {
            short8 vf = *(const short8*)&Vts[nt * 16 + l16][quad * 8];
            o_acc[nt] = MFMA(pfu.s8, vf, o_acc[nt], 0, 0, 0);
        }
    }

    // epilogue: o_acc rows are q = quad*4 + r; 1/l lives at lane l16 = q
    const float inv = 1.f / l;
    float ir[4];
    #pragma unroll
    for (int r = 0; r < 4; ++r) ir[r] = __shfl(inv, quad * 4 + r);
    const size_t aob = ((size_t)b * Nn + i0 + wave * 16) * DIMc + h * DHd;
    #pragma unroll
    for (int nt = 0; nt < 4; ++nt)
        #pragma unroll
        for (int r = 0; r < 4; ++r) {
            unsigned short hi, lo;
            split_trunc(o_acc[nt][r] * ir[r], hi, lo);
            const size_t off = aob + (size_t)(quad * 4 + r) * DIMc + nt * 16 + l16;
            AOh[off] = hi;
            AOl[off] = lo;
        }
}

// ---------------------------------------------------------------------------
// GEMM2 (MFMA, 3-term split): out = AO @ W_out + b_out ; all operands bf16 hi/lo.
// ---------------------------------------------------------------------------
__global__ __launch_bounds__(256) void gemm_out_mfma(
    const unsigned short* __restrict__ Agh, const unsigned short* __restrict__ Agl,
    const unsigned short* __restrict__ Wh, const unsigned short* __restrict__ Wl,
    const float* __restrict__ bias, float* __restrict__ C)
{
    __shared__ struct { unsigned short Ah[4096], Al[4096], Bh[4096], Bl[4096]; } s;

    const int tid  = threadIdx.x;
    const int w    = tid >> 6;
    const int lane = tid & 63;
    const int quad = lane >> 4;
    const int l16  = lane & 15;
    const int n0 = blockIdx.x * 128;
    const int m0 = blockIdx.y * 128;
    const int wm = w >> 1, wn = w & 1;

    floatx4 acc[4][4];
    #pragma unroll
    for (int im = 0; im < 4; ++im)
        #pragma unroll
        for (int in = 0; in < 4; ++in)
            acc[im][in] = (floatx4){0.f, 0.f, 0.f, 0.f};

    for (int k0 = 0; k0 < GK; k0 += 32) {
        short8 ah8[2], al8[2], wbh[2], wbl[2];
        #pragma unroll
        for (int i = 0; i < 2; ++i) {
            const int row = i * 64 + w * 16 + l16;
            const size_t aoff = (size_t)(m0 + row) * GK + k0 + quad * 8;
            ah8[i] = *(const short8*)(Agh + aoff);
            al8[i] = *(const short8*)(Agl + aoff);
            const size_t boff = (size_t)(n0 + row) * GK + k0 + quad * 8;
            wbh[i] = *(const short8*)(Wh + boff);
            wbl[i] = *(const short8*)(Wl + boff);
        }
        __syncthreads();
        #pragma unroll
        for (int i = 0; i < 2; ++i) {
            const int ci = ((i * 4 + w) * 4 + quad) * 16 + l16;
            *(short8*)&s.Ah[ci * 8] = ah8[i];
            *(short8*)&s.Al[ci * 8] = al8[i];
            *(short8*)&s.Bh[ci * 8] = wbh[i];
            *(short8*)&s.Bl[ci * 8] = wbl[i];
        }
        __syncthreads();

        short8 fah[4], fal[4], fbh[4], fbl[4];
        #pragma unroll
        for (int t = 0; t < 4; ++t) {
            const int ca = ((wm * 4 + t) * 4 + quad) * 16 + l16;
            fah[t] = *(const short8*)&s.Ah[ca * 8];
            fal[t] = *(const short8*)&s.Al[ca * 8];
            const int cb = ((wn * 4 + t) * 4 + quad) * 16 + l16;
            fbh[t] = *(const short8*)&s.Bh[cb * 8];
            fbl[t] = *(const short8*)&s.Bl[cb * 8];
        }
        #pragma unroll
        for (int im = 0; im < 4; ++im)
            #pragma unroll
            for (int in = 0; in < 4; ++in) {
                floatx4 a = acc[im][in];
                a = MFMA(fah[im], fbh[in], a, 0, 0, 0);
                a = MFMA(fal[im], fbh[in], a, 0, 0, 0);
                a = MFMA(fah[im], fbl[in], a, 0, 0, 0);
                acc[im][in] = a;
            }
    }

    float biasv[4];
    #pragma unroll
    for (int in = 0; in < 4; ++in) biasv[in] = bias[n0 + wn * 64 + in * 16 + l16];
    #pragma unroll
    for (int im = 0; im < 4; ++im)
        #pragma unroll
        for (int in = 0; in < 4; ++in) {
            const int mrow = m0 + wm * 64 + im * 16 + quad * 4;
            const int ncol = n0 + wn * 64 + in * 16 + l16;
            #pragma unroll
            for (int r = 0; r < 4; ++r)
                C[(size_t)(mrow + r) * DIMc + ncol] = acc[im][in][r] + biasv[in];
        }
}

// ---------------------------------------------------------------------------
extern "C" void kernel_launch(void* const* d_in, const int* in_sizes, int n_in,
                              void* d_out, int out_size, void* d_ws, size_t ws_size,
                              hipStream_t stream)
{
    const float* x     = (const float*)d_in[0];
    const float* Wqkv  = (const float*)d_in[1];
    const float* Wout  = (const float*)d_in[2];
    const float* bout  = (const float*)d_in[3];
    const float* decay = (const float*)d_in[4];

    const size_t E = (size_t)32768 * 512;   // 16,777,216
    unsigned short* p = (unsigned short*)d_ws;
    unsigned short* Qh  = p; p += E;
    unsigned short* Ql  = p; p += E;
    unsigned short* Kh  = p; p += E;
    unsigned short* Kl  = p; p += E;
    unsigned short* Vt  = p; p += E;
    unsigned short* AOh = p; p += E;
    unsigned short* AOl = p; p += E;
    unsigned short* Wqh = p; p += 786432;
    unsigned short* Wql = p; p += 786432;
    unsigned short* Woh = p; p += 262144;
    unsigned short* Wol = p; p += 262144;
    unsigned short* D16 = p;               // 8,388,608 halves
    // total: ~244 MiB (< the 256 MiB round-0 proved available)

    transpose_split_kernel<<<dim3(48, 16), 256, 0, stream>>>(Wqkv, 512, 1536, Wqh, Wql);
    transpose_split_kernel<<<dim3(16, 16), 256, 0, stream>>>(Wout, 512, 512, Woh, Wol);
    decay_to_half_kernel<<<dim3(8192), 256, 0, stream>>>(decay, D16);
    gemm_qkv_mfma<<<dim3(12, 256), 256, 0, stream>>>(x, Wqh, Wql, Qh, Ql, Kh, Kl, Vt);
    attn_mfma_kernel<<<dim3(256, 16), 256, 0, stream>>>(Qh, Ql, Kh, Kl, Vt, D16, AOh, AOl);
    gemm_out_mfma<<<dim3(4, 256), 256, 0, stream>>>(AOh, AOl, Woh, Wol, bout, (float*)d_out);
}

// Round 2
// 558.953 us; speedup vs baseline: 1.2417x; 1.0350x over previous
//
#include <hip/hip_runtime.h>
#include <hip/hip_fp16.h>
#include <math.h>

// Problem constants
#define Bb 32
#define Nn 1024
#define DIMc 512
#define Hh 8
#define DHd 64
#define GK 512          // K for both projection GEMMs

typedef __attribute__((ext_vector_type(8))) short short8;   // 8 bf16 (4 VGPRs)
typedef __attribute__((ext_vector_type(4))) float floatx4;  // MFMA 16x16 acc

#define MFMA __builtin_amdgcn_mfma_f32_16x16x32_bf16

#if __has_builtin(__builtin_amdgcn_exp2f)
#define EXP2(x) __builtin_amdgcn_exp2f(x)
#else
#define EXP2(x) __expf((x) * 0.6931471805599453f)
#endif

__device__ __forceinline__ unsigned short bf16_rtn(float f) {
    unsigned int u = __float_as_uint(f);
    u += 0x7FFFu + ((u >> 16) & 1u);     // round-to-nearest-even
    return (unsigned short)(u >> 16);
}
__device__ __forceinline__ float bf16_to_f32(unsigned short h) {
    return __uint_as_float(((unsigned int)h) << 16);
}
// Truncation split: f == hi + lo exactly in fp32 (Dekker-style); lo then
// truncated to bf16 (residual of residual ~2^-16 rel -- below noise floor).
__device__ __forceinline__ void split_trunc(float f, unsigned short& hi, unsigned short& lo) {
    unsigned int u = __float_as_uint(f) & 0xFFFF0000u;
    hi = (unsigned short)(u >> 16);
    float rest = f - __uint_as_float(u);
    lo = (unsigned short)(__float_as_uint(rest) >> 16);
}
// pack 2 fp32 -> 2 bf16 in one dword (lo -> bits 0..15, hi -> bits 16..31)
__device__ __forceinline__ int cvt_pk_bf16(float lo, float hi) {
    int r;
    asm("v_cvt_pk_bf16_f32 %0, %1, %2" : "=v"(r) : "v"(lo), "v"(hi));
    return r;
}
// async global->LDS, 16 bytes per lane; LDS dest = wave-uniform base + lane*16
__device__ __forceinline__ void gload_lds16(const unsigned short* g, unsigned short* l) {
    __builtin_amdgcn_global_load_lds(
        (const __attribute__((address_space(1))) unsigned int*)g,
        (__attribute__((address_space(3))) unsigned int*)l,
        16, 0, 0);
}

// ---------------------------------------------------------------------------
// Prep 1: transpose + split fp32 weight [K][N] -> hi/lo bf16 [N][K]
// ---------------------------------------------------------------------------
__global__ __launch_bounds__(256) void transpose_split_kernel(
    const float* __restrict__ src, int K, int N,
    unsigned short* __restrict__ dh, unsigned short* __restrict__ dl)
{
    __shared__ float T[32][33];
    const int tid = threadIdx.x;
    const int c = tid & 31, r0 = tid >> 5;
    const int nb = blockIdx.x * 32, kb = blockIdx.y * 32;
    #pragma unroll
    for (int i = 0; i < 4; ++i)
        T[r0 + i * 8][c] = src[(size_t)(kb + r0 + i * 8) * N + nb + c];
    __syncthreads();
    #pragma unroll
    for (int i = 0; i < 4; ++i) {
        int n = r0 + i * 8;
        unsigned short hi, lo;
        split_trunc(T[c][n], hi, lo);
        size_t off = (size_t)(nb + n) * K + kb + c;
        dh[off] = hi;
        dl[off] = lo;
    }
}

// ---------------------------------------------------------------------------
// Prep 2: decay fp32 -> fp16 (post-softmax multiplier; fp16 rel err ~5e-4)
// ---------------------------------------------------------------------------
__global__ __launch_bounds__(256) void decay_to_half_kernel(
    const float* __restrict__ D, unsigned short* __restrict__ D16)
{
    size_t i = ((size_t)blockIdx.x * 256 + threadIdx.x) * 4;
    float4 v = *(const float4*)(D + i);
    ushort4 o;
    o.x = __half_as_ushort(__float2half(v.x));
    o.y = __half_as_ushort(__float2half(v.y));
    o.z = __half_as_ushort(__float2half(v.z));
    o.w = __half_as_ushort(__float2half(v.w));
    *(ushort4*)(D16 + i) = o;
}

// ---------------------------------------------------------------------------
// Prep 3: split fp32 activations X -> hi/lo bf16 (done ONCE; the GEMM used to
// redo this split 12x, once per N-tile). Xh/Xl alias AOh/AOl (dead until attn).
// ---------------------------------------------------------------------------
__global__ __launch_bounds__(256) void split_x_kernel(
    const float* __restrict__ X,
    unsigned short* __restrict__ Xh, unsigned short* __restrict__ Xl)
{
    size_t i = ((size_t)blockIdx.x * 256 + threadIdx.x) * 8;
    float4 a = *(const float4*)(X + i);
    float4 b = *(const float4*)(X + i + 4);
    float f[8] = {a.x, a.y, a.z, a.w, b.x, b.y, b.z, b.w};
    short8 hi, lo;
    #pragma unroll
    for (int e = 0; e < 8; ++e) {
        unsigned short h_, l_;
        split_trunc(f[e], h_, l_);
        hi[e] = (short)h_;
        lo[e] = (short)l_;
    }
    *(short8*)(Xh + i) = hi;
    *(short8*)(Xl + i) = lo;
}

// ---------------------------------------------------------------------------
// GEMM1 (MFMA, 3-term split): qkv = x @ W_qkv
// All four staged operands are pre-split bf16 in global; staging is pure
// global_load_lds width=16 (no VGPR round-trip, no repack VALU, no ds_write).
// LDS frag layout byte offset = (i*4+w)*1024 + lane*16  ==  glds dest order.
// Q epilogue folds SCALE * log2(e) so attention exps are raw v_exp_f32.
// ---------------------------------------------------------------------------
__global__ __launch_bounds__(256) void gemm_qkv_mfma(
    const unsigned short* __restrict__ Xh, const unsigned short* __restrict__ Xl,
    const unsigned short* __restrict__ Wh, const unsigned short* __restrict__ Wl,
    unsigned short* __restrict__ Qh, unsigned short* __restrict__ Ql,
    unsigned short* __restrict__ Kh, unsigned short* __restrict__ Kl,
    unsigned short* __restrict__ Vt)
{
    __shared__ union {
        struct { unsigned short Ah[4096], Al[4096], Bh[4096], Bl[4096]; } s;
        unsigned short bounce[128][136];   // V-transpose bounce (epilogue only)
    } u;

    const int tid  = threadIdx.x;
    const int w    = tid >> 6;
    const int lane = tid & 63;
    const int quad = lane >> 4;
    const int l16  = lane & 15;
    const int n0 = blockIdx.x * 128;
    const int m0 = blockIdx.y * 128;
    const int wm = w >> 1, wn = w & 1;

    floatx4 acc[4][4];
    #pragma unroll
    for (int im = 0; im < 4; ++im)
        #pragma unroll
        for (int in = 0; in < 4; ++in)
            acc[im][in] = (floatx4){0.f, 0.f, 0.f, 0.f};

    for (int k0 = 0; k0 < GK; k0 += 32) {
        __syncthreads();                    // all frag reads of prev tile done
        #pragma unroll
        for (int i = 0; i < 2; ++i) {
            const int row = i * 64 + w * 16 + l16;
            const size_t aoff = (size_t)(m0 + row) * GK + k0 + quad * 8;
            const size_t boff = (size_t)(n0 + row) * GK + k0 + quad * 8;
            const int lb = (i * 4 + w) * 512;   // element base (bytes = *2)
            gload_lds16(Xh + aoff, &u.s.Ah[lb]);
            gload_lds16(Xl + aoff, &u.s.Al[lb]);
            gload_lds16(Wh + boff, &u.s.Bh[lb]);
            gload_lds16(Wl + boff, &u.s.Bl[lb]);
        }
        __syncthreads();                    // drains vmcnt: LDS tile ready

        short8 fah[4], fal[4], fbh[4], fbl[4];
        #pragma unroll
        for (int t = 0; t < 4; ++t) {
            const int ca = ((wm * 4 + t) * 4 + quad) * 16 + l16;
            fah[t] = *(const short8*)&u.s.Ah[ca * 8];
            fal[t] = *(const short8*)&u.s.Al[ca * 8];
            const int cb = ((wn * 4 + t) * 4 + quad) * 16 + l16;
            fbh[t] = *(const short8*)&u.s.Bh[cb * 8];
            fbl[t] = *(const short8*)&u.s.Bl[cb * 8];
        }
        #pragma unroll
        for (int im = 0; im < 4; ++im)
            #pragma unroll
            for (int in = 0; in < 4; ++in) {
                floatx4 a = acc[im][in];
                a = MFMA(fah[im], fbh[in], a, 0, 0, 0);
                a = MFMA(fal[im], fbh[in], a, 0, 0, 0);
                a = MFMA(fah[im], fbl[in], a, 0, 0, 0);
                acc[im][in] = a;
            }
    }

    // ---- epilogue ----
    const int which = n0 >> 9;       // 0=q 1=k 2=v (128-tiles never straddle)
    const int b    = m0 >> 10;
    const int tokb = m0 & 1023;
    if (which < 2) {
        unsigned short* HI = which ? Kh : Qh;
        unsigned short* LO = which ? Kl : Ql;
        // Q: fold SCALE * log2(e) = 0.125 * 1.4426950408889634
        const float sc = which ? 1.0f : 0.18033688011112042f;
        #pragma unroll
        for (int im = 0; im < 4; ++im) {
            const int tok = tokb + wm * 64 + im * 16 + quad * 4;
            #pragma unroll
            for (int in = 0; in < 4; ++in) {
                const int ncol = n0 + wn * 64 + in * 16 + l16;
                const int h = (ncol & 511) >> 6, d = ncol & 63;
                const size_t base = ((size_t)(b * Hh + h) * Nn + tok) * DHd + d;
                #pragma unroll
                for (int r = 0; r < 4; ++r) {
                    unsigned short hi, lo;
                    split_trunc(acc[im][in][r] * sc, hi, lo);
                    HI[base + (size_t)r * DHd] = hi;
                    LO[base + (size_t)r * DHd] = lo;
                }
            }
        }
    } else {
        // V: bf16 + transpose through LDS bounce -> Vt [bh][64][1024]
        __syncthreads();
        #pragma unroll
        for (int im = 0; im < 4; ++im)
            #pragma unroll
            for (int in = 0; in < 4; ++in)
                #pragma unroll
                for (int r = 0; r < 4; ++r)
                    u.bounce[wm * 64 + im * 16 + quad * 4 + r][wn * 64 + in * 16 + l16] =
                        bf16_rtn(acc[im][in][r]);
        __syncthreads();
        const int c = tid >> 1, tq = (tid & 1) * 64;
        const int h = ((n0 + c) & 511) >> 6, d = c & 63;
        unsigned short* vbase = Vt + ((size_t)(b * Hh + h) * DHd + d) * Nn + tokb;
        #pragma unroll
        for (int uu = 0; uu < 8; ++uu) {
            short8 v8;
            #pragma unroll
            for (int e = 0; e < 8; ++e)
                v8[e] = (short)u.bounce[tq + uu * 8 + e][c];
            *(short8*)&vbase[tq + uu * 8] = v8;
        }
    }
}

// ---------------------------------------------------------------------------
// MFMA flash attention (unchanged this round): swapped QK^T, in-register P,
// defer-max, async-STAGE prefetch.
// ---------------------------------------------------------------------------
__global__ __launch_bounds__(256) void attn_mfma_kernel(
    const unsigned short* __restrict__ Qh, const unsigned short* __restrict__ Ql,
    const unsigned short* __restrict__ Kh, const unsigned short* __restrict__ Kl,
    const unsigned short* __restrict__ Vt, const unsigned short* __restrict__ D16,
    unsigned short* __restrict__ AOh, unsigned short* __restrict__ AOl)
{
    __shared__ unsigned short Khs[32][72];   // [permuted j][d]
    __shared__ unsigned short Kls[32][72];
    __shared__ unsigned short Vts[64][40];   // [d][j]

    const int tid  = threadIdx.x;
    const int wave = tid >> 6;
    const int lane = tid & 63;
    const int quad = lane >> 4;
    const int l16  = lane & 15;
    const int bh   = blockIdx.x;
    const int b    = bh >> 3, h = bh & 7;
    const int i0   = blockIdx.y * 64;
    const int iw   = i0 + wave * 16;

    const size_t qoff = ((size_t)bh * Nn + iw + l16) * DHd + quad * 8;
    const short8 qh0 = *(const short8*)(Qh + qoff);
    const short8 qh1 = *(const short8*)(Qh + qoff + 32);
    const short8 ql0 = *(const short8*)(Ql + qoff);
    const short8 ql1 = *(const short8*)(Ql + qoff + 32);

    floatx4 o_acc[4];
    #pragma unroll
    for (int nt = 0; nt < 4; ++nt) o_acc[nt] = (floatx4){0.f, 0.f, 0.f, 0.f};
    float m = -INFINITY;      // per-lane: row q = l16 (replicated across quads)
    float l = 0.f;

    const int sj  = tid >> 3, sc2 = (tid & 7) * 8;       // K tiles: 32 x 64
    const int prow = ((sj >> 2) & 1) * 16 + ((sj >> 3) << 2) + (sj & 3);
    const int vd  = tid >> 2, vj8 = (tid & 3) * 8;       // Vt tile: 64 x 32
    const size_t kbase  = (size_t)bh * Nn * DHd;
    const size_t vtbase = (size_t)bh * DHd * Nn;
    const unsigned short* Dp = D16 + ((size_t)h * Nn + iw + l16) * Nn + quad * 8;

    short8 pk_h = *(const short8*)&Kh[kbase + (size_t)sj * DHd + sc2];
    short8 pk_l = *(const short8*)&Kl[kbase + (size_t)sj * DHd + sc2];
    short8 pk_v = *(const short8*)&Vt[vtbase + (size_t)vd * Nn + vj8];

    for (int j0 = 0; j0 < Nn; j0 += 32) {
        const short8 dc = *(const short8*)(Dp + j0);     // 8 fp16 decay values
        __syncthreads();
        *(short8*)&Khs[prow][sc2] = pk_h;
        *(short8*)&Kls[prow][sc2] = pk_l;
        *(short8*)&Vts[vd][vj8]   = pk_v;
        __syncthreads();
        {   // T14: issue next tile's loads now; latency hides under compute
            const int jn = (j0 + 32) & (Nn - 1);
            pk_h = *(const short8*)&Kh[kbase + (size_t)(jn + sj) * DHd + sc2];
            pk_l = *(const short8*)&Kl[kbase + (size_t)(jn + sj) * DHd + sc2];
            pk_v = *(const short8*)&Vt[vtbase + (size_t)vd * Nn + jn + vj8];
        }

        floatx4 sacc[2];
        #pragma unroll
        for (int nh = 0; nh < 2; ++nh) {
            const int kr = nh * 16 + l16;
            short8 kh0 = *(const short8*)&Khs[kr][quad * 8];
            short8 kh1 = *(const short8*)&Khs[kr][32 + quad * 8];
            short8 kl0 = *(const short8*)&Kls[kr][quad * 8];
            short8 kl1 = *(const short8*)&Kls[kr][32 + quad * 8];
            floatx4 a = (floatx4){0.f, 0.f, 0.f, 0.f};
            a = MFMA(kh0, qh0, a, 0, 0, 0);
            a = MFMA(kh1, qh1, a, 0, 0, 0);
            a = MFMA(kl0, qh0, a, 0, 0, 0);
            a = MFMA(kl1, qh1, a, 0, 0, 0);
            a = MFMA(kh0, ql0, a, 0, 0, 0);
            a = MFMA(kh1, ql1, a, 0, 0, 0);
            sacc[nh] = a;
        }

        float t = fmaxf(fmaxf(fmaxf(sacc[0][0], sacc[0][1]), fmaxf(sacc[0][2], sacc[0][3])),
                        fmaxf(fmaxf(sacc[1][0], sacc[1][1]), fmaxf(sacc[1][2], sacc[1][3])));
        t = fmaxf(t, __shfl_xor(t, 16));
        t = fmaxf(t, __shfl_xor(t, 32));

        if (!__all(t <= m + 8.0f)) {
            const float nm = fmaxf(m, t);
            const float fac = EXP2(m - nm);
            m = nm;
            l *= fac;
            float fr[4];
            #pragma unroll
            for (int r = 0; r < 4; ++r) fr[r] = __shfl(fac, quad * 4 + r);
            #pragma unroll
            for (int nt = 0; nt < 4; ++nt) {
                floatx4 t4 = o_acc[nt];
                t4[0] *= fr[0]; t4[1] *= fr[1]; t4[2] *= fr[2]; t4[3] *= fr[3];
                o_acc[nt] = t4;
            }
        }

        float p[8];
        #pragma unroll
        for (int e = 0; e < 4; ++e) p[e]     = EXP2(sacc[0][e] - m);
        #pragma unroll
        for (int e = 0; e < 4; ++e) p[4 + e] = EXP2(sacc[1][e] - m);
        float ps = ((p[0] + p[1]) + (p[2] + p[3])) + ((p[4] + p[5]) + (p[6] + p[7]));
        ps += __shfl_xor(ps, 16);
        ps += __shfl_xor(ps, 32);
        l += ps;                               // denom WITHOUT decay

        union { int i4[4]; short8 s8; } pfu;
        #pragma unroll
        for (int e = 0; e < 4; ++e) {
            const float d0 = __half2float(__ushort_as_half((unsigned short)dc[2 * e]));
            const float d1 = __half2float(__ushort_as_half((unsigned short)dc[2 * e + 1]));
            pfu.i4[e] = cvt_pk_bf16(p[2 * e] * d0, p[2 * e + 1] * d1);
        }
        #pragma unroll
        for (int nt = 0; nt < 4; ++nt) {
            short8 vf = *(const short8*)&Vts[nt * 16 + l16][quad * 8];
            o_acc[nt] = MFMA(pfu.s8, vf, o_acc[nt], 0, 0, 0);
        }
    }

    const float inv = 1.f / l;
    float ir[4];
    #pragma unroll
    for (int r = 0; r < 4; ++r) ir[r] = __shfl(inv, quad * 4 + r);
    const size_t aob = ((size_t)b * Nn + i0 + wave * 16) * DIMc + h * DHd;
    #pragma unroll
    for (int nt = 0; nt < 4; ++nt)
        #pragma unroll
        for (int r = 0; r < 4; ++r) {
            unsigned short hi, lo;
            split_trunc(o_acc[nt][r] * ir[r], hi, lo);
            const size_t off = aob + (size_t)(quad * 4 + r) * DIMc + nt * 16 + l16;
            AOh[off] = hi;
            AOl[off] = lo;
        }
}

// ---------------------------------------------------------------------------
// GEMM2 (MFMA, 3-term split): out = AO @ W_out + b_out ; staging now pure
// global_load_lds width=16 (operands already bf16 hi/lo in global).
// ---------------------------------------------------------------------------
__global__ __launch_bounds__(256) void gemm_out_mfma(
    const unsigned short* __restrict__ Agh, const unsigned short* __restrict__ Agl,
    const unsigned short* __restrict__ Wh, const unsigned short* __restrict__ Wl,
    const float* __restrict__ bias, float* __restrict__ C)
{
    __shared__ struct { unsigned short Ah[4096], Al[4096], Bh[4096], Bl[4096]; } s;

    const int tid  = threadIdx.x;
    const int w    = tid >> 6;
    const int lane = tid & 63;
    const int quad = lane >> 4;
    const int l16  = lane & 15;
    const int n0 = blockIdx.x * 128;
    const int m0 = blockIdx.y * 128;
    const int wm = w >> 1, wn = w & 1;

    floatx4 acc[4][4];
    #pragma unroll
    for (int im = 0; im < 4; ++im)
        #pragma unroll
        for (int in = 0; in < 4; ++in)
            acc[im][in] = (floatx4){0.f, 0.f, 0.f, 0.f};

    for (int k0 = 0; k0 < GK; k0 += 32) {
        __syncthreads();
        #pragma unroll
        for (int i = 0; i < 2; ++i) {
            const int row = i * 64 + w * 16 + l16;
            const size_t aoff = (size_t)(m0 + row) * GK + k0 + quad * 8;
            const size_t boff = (size_t)(n0 + row) * GK + k0 + quad * 8;
            const int lb = (i * 4 + w) * 512;
            gload_lds16(Agh + aoff, &s.Ah[lb]);
            gload_lds16(Agl + aoff, &s.Al[lb]);
            gload_lds16(Wh + boff, &s.Bh[lb]);
            gload_lds16(Wl + boff, &s.Bl[lb]);
        }
        __syncthreads();

        short8 fah[4], fal[4], fbh[4], fbl[4];
        #pragma unroll
        for (int t = 0; t < 4; ++t) {
            const int ca = ((wm * 4 + t) * 4 + quad) * 16 + l16;
            fah[t] = *(const short8*)&s.Ah[ca * 8];
            fal[t] = *(const short8*)&s.Al[ca * 8];
            const int cb = ((wn * 4 + t) * 4 + quad) * 16 + l16;
            fbh[t] = *(const short8*)&s.Bh[cb * 8];
            fbl[t] = *(const short8*)&s.Bl[cb * 8];
        }
        #pragma unroll
        for (int im = 0; im < 4; ++im)
            #pragma unroll
            for (int in = 0; in < 4; ++in) {
                floatx4 a = acc[im][in];
                a = MFMA(fah[im], fbh[in], a, 0, 0, 0);
                a = MFMA(fal[im], fbh[in], a, 0, 0, 0);
                a = MFMA(fah[im], fbl[in], a, 0, 0, 0);
                acc[im][in] = a;
            }
    }

    float biasv[4];
    #pragma unroll
    for (int in = 0; in < 4; ++in) biasv[in] = bias[n0 + wn * 64 + in * 16 + l16];
    #pragma unroll
    for (int im = 0; im < 4; ++im)
        #pragma unroll
        for (int in = 0; in < 4; ++in) {
            const int mrow = m0 + wm * 64 + im * 16 + quad * 4;
            const int ncol = n0 + wn * 64 + in * 16 + l16;
            #pragma unroll
            for (int r = 0; r < 4; ++r)
                C[(size_t)(mrow + r) * DIMc + ncol] = acc[im][in][r] + biasv[in];
        }
}

// ---------------------------------------------------------------------------
extern "C" void kernel_launch(void* const* d_in, const int* in_sizes, int n_in,
                              void* d_out, int out_size, void* d_ws, size_t ws_size,
                              hipStream_t stream)
{
    const float* x     = (const float*)d_in[0];
    const float* Wqkv  = (const float*)d_in[1];
    const float* Wout  = (const float*)d_in[2];
    const float* bout  = (const float*)d_in[3];
    const float* decay = (const float*)d_in[4];

    const size_t E = (size_t)32768 * 512;   // 16,777,216
    unsigned short* p = (unsigned short*)d_ws;
    unsigned short* Qh  = p; p += E;
    unsigned short* Ql  = p; p += E;
    unsigned short* Kh  = p; p += E;
    unsigned short* Kl  = p; p += E;
    unsigned short* Vt  = p; p += E;
    unsigned short* AOh = p; p += E;
    unsigned short* AOl = p; p += E;
    unsigned short* Wqh = p; p += 786432;
    unsigned short* Wql = p; p += 786432;
    unsigned short* Woh = p; p += 262144;
    unsigned short* Wol = p; p += 262144;
    unsigned short* D16 = p;               // 8,388,608 halves
    // total: ~244 MiB. Xh/Xl ALIAS AOh/AOl: X's split is dead before attn
    // writes AO (stream-serialized), so no extra workspace.
    unsigned short* Xh = AOh;
    unsigned short* Xl = AOl;

    transpose_split_kernel<<<dim3(48, 16), 256, 0, stream>>>(Wqkv, 512, 1536, Wqh, Wql);
    transpose_split_kernel<<<dim3(16, 16), 256, 0, stream>>>(Wout, 512, 512, Woh, Wol);
    decay_to_half_kernel<<<dim3(8192), 256, 0, stream>>>(decay, D16);
    split_x_kernel<<<dim3(8192), 256, 0, stream>>>(x, Xh, Xl);
    gemm_qkv_mfma<<<dim3(12, 256), 256, 0, stream>>>(Xh, Xl, Wqh, Wql, Qh, Ql, Kh, Kl, Vt);
    attn_mfma_kernel<<<dim3(256, 16), 256, 0, stream>>>(Qh, Ql, Kh, Kl, Vt, D16, AOh, AOl);
    gemm_out_mfma<<<dim3(4, 256), 256, 0, stream>>>(AOh, AOl, Woh, Wol, bout, (float*)d_out);
}

// Round 3
// 534.672 us; speedup vs baseline: 1.2981x; 1.0454x over previous
//
#include <hip/hip_runtime.h>
#include <hip/hip_fp16.h>
#include <math.h>

// Problem constants
#define Bb 32
#define Nn 1024
#define DIMc 512
#define Hh 8
#define DHd 64
#define GK 512          // K for both projection GEMMs

typedef __attribute__((ext_vector_type(8))) short short8;   // 8 bf16 (4 VGPRs)
typedef __attribute__((ext_vector_type(4))) float floatx4;  // MFMA 16x16 acc

#define MFMA __builtin_amdgcn_mfma_f32_16x16x32_bf16

#if __has_builtin(__builtin_amdgcn_exp2f)
#define EXP2(x) __builtin_amdgcn_exp2f(x)
#else
#define EXP2(x) __expf((x) * 0.6931471805599453f)
#endif

__device__ __forceinline__ unsigned short bf16_rtn(float f) {
    unsigned int u = __float_as_uint(f);
    u += 0x7FFFu + ((u >> 16) & 1u);     // round-to-nearest-even
    return (unsigned short)(u >> 16);
}
__device__ __forceinline__ float bf16_to_f32(unsigned short h) {
    return __uint_as_float(((unsigned int)h) << 16);
}
// Truncation split: f == hi + lo exactly in fp32 (Dekker-style); lo then
// truncated to bf16 (residual of residual ~2^-16 rel -- below noise floor).
__device__ __forceinline__ void split_trunc(float f, unsigned short& hi, unsigned short& lo) {
    unsigned int u = __float_as_uint(f) & 0xFFFF0000u;
    hi = (unsigned short)(u >> 16);
    float rest = f - __uint_as_float(u);
    lo = (unsigned short)(__float_as_uint(rest) >> 16);
}
// pack 2 fp32 -> 2 bf16 in one dword (lo -> bits 0..15, hi -> bits 16..31)
__device__ __forceinline__ int cvt_pk_bf16(float lo, float hi) {
    int r;
    asm("v_cvt_pk_bf16_f32 %0, %1, %2" : "=v"(r) : "v"(lo), "v"(hi));
    return r;
}
// async global->LDS, 16 bytes per lane; LDS dest = wave-uniform base + lane*16
__device__ __forceinline__ void gload_lds16(const unsigned short* g, unsigned short* l) {
    __builtin_amdgcn_global_load_lds(
        (const __attribute__((address_space(1))) unsigned int*)g,
        (__attribute__((address_space(3))) unsigned int*)l,
        16, 0, 0);
}

// ---------------------------------------------------------------------------
// Prep 1: transpose + split fp32 weight [K][N] -> hi/lo bf16 [N][K]
// ---------------------------------------------------------------------------
__global__ __launch_bounds__(256) void transpose_split_kernel(
    const float* __restrict__ src, int K, int N,
    unsigned short* __restrict__ dh, unsigned short* __restrict__ dl)
{
    __shared__ float T[32][33];
    const int tid = threadIdx.x;
    const int c = tid & 31, r0 = tid >> 5;
    const int nb = blockIdx.x * 32, kb = blockIdx.y * 32;
    #pragma unroll
    for (int i = 0; i < 4; ++i)
        T[r0 + i * 8][c] = src[(size_t)(kb + r0 + i * 8) * N + nb + c];
    __syncthreads();
    #pragma unroll
    for (int i = 0; i < 4; ++i) {
        int n = r0 + i * 8;
        unsigned short hi, lo;
        split_trunc(T[c][n], hi, lo);
        size_t off = (size_t)(nb + n) * K + kb + c;
        dh[off] = hi;
        dl[off] = lo;
    }
}

// ---------------------------------------------------------------------------
// Prep 2: decay fp32 -> fp16 (post-softmax multiplier; fp16 rel err ~5e-4)
// ---------------------------------------------------------------------------
__global__ __launch_bounds__(256) void decay_to_half_kernel(
    const float* __restrict__ D, unsigned short* __restrict__ D16)
{
    size_t i = ((size_t)blockIdx.x * 256 + threadIdx.x) * 4;
    float4 v = *(const float4*)(D + i);
    ushort4 o;
    o.x = __half_as_ushort(__float2half(v.x));
    o.y = __half_as_ushort(__float2half(v.y));
    o.z = __half_as_ushort(__float2half(v.z));
    o.w = __half_as_ushort(__float2half(v.w));
    *(ushort4*)(D16 + i) = o;
}

// ---------------------------------------------------------------------------
// Prep 3: split fp32 activations X -> hi/lo bf16 (done ONCE; the GEMM used to
// redo this split 12x, once per N-tile). Xh/Xl alias AOh/AOl (dead until attn).
// ---------------------------------------------------------------------------
__global__ __launch_bounds__(256) void split_x_kernel(
    const float* __restrict__ X,
    unsigned short* __restrict__ Xh, unsigned short* __restrict__ Xl)
{
    size_t i = ((size_t)blockIdx.x * 256 + threadIdx.x) * 8;
    float4 a = *(const float4*)(X + i);
    float4 b = *(const float4*)(X + i + 4);
    float f[8] = {a.x, a.y, a.z, a.w, b.x, b.y, b.z, b.w};
    short8 hi, lo;
    #pragma unroll
    for (int e = 0; e < 8; ++e) {
        unsigned short h_, l_;
        split_trunc(f[e], h_, l_);
        hi[e] = (short)h_;
        lo[e] = (short)l_;
    }
    *(short8*)(Xh + i) = hi;
    *(short8*)(Xl + i) = lo;
}

// ---------------------------------------------------------------------------
// GEMM1 (MFMA, 3-term split): qkv = x @ W_qkv
// All four staged operands are pre-split bf16 in global; staging is pure
// global_load_lds width=16 (no VGPR round-trip, no repack VALU, no ds_write).
// LDS frag layout byte offset = (i*4+w)*1024 + lane*16  ==  glds dest order.
// Q epilogue folds SCALE * log2(e) so attention exps are raw v_exp_f32.
// ---------------------------------------------------------------------------
__global__ __launch_bounds__(256) void gemm_qkv_mfma(
    const unsigned short* __restrict__ Xh, const unsigned short* __restrict__ Xl,
    const unsigned short* __restrict__ Wh, const unsigned short* __restrict__ Wl,
    unsigned short* __restrict__ Qh, unsigned short* __restrict__ Ql,
    unsigned short* __restrict__ Kh, unsigned short* __restrict__ Kl,
    unsigned short* __restrict__ Vt)
{
    __shared__ union {
        struct { unsigned short Ah[4096], Al[4096], Bh[4096], Bl[4096]; } s;
        unsigned short bounce[128][136];   // V-transpose bounce (epilogue only)
    } u;

    const int tid  = threadIdx.x;
    const int w    = tid >> 6;
    const int lane = tid & 63;
    const int quad = lane >> 4;
    const int l16  = lane & 15;
    const int n0 = blockIdx.x * 128;
    const int m0 = blockIdx.y * 128;
    const int wm = w >> 1, wn = w & 1;

    floatx4 acc[4][4];
    #pragma unroll
    for (int im = 0; im < 4; ++im)
        #pragma unroll
        for (int in = 0; in < 4; ++in)
            acc[im][in] = (floatx4){0.f, 0.f, 0.f, 0.f};

    for (int k0 = 0; k0 < GK; k0 += 32) {
        __syncthreads();                    // all frag reads of prev tile done
        #pragma unroll
        for (int i = 0; i < 2; ++i) {
            const int row = i * 64 + w * 16 + l16;
            const size_t aoff = (size_t)(m0 + row) * GK + k0 + quad * 8;
            const size_t boff = (size_t)(n0 + row) * GK + k0 + quad * 8;
            const int lb = (i * 4 + w) * 512;   // element base (bytes = *2)
            gload_lds16(Xh + aoff, &u.s.Ah[lb]);
            gload_lds16(Xl + aoff, &u.s.Al[lb]);
            gload_lds16(Wh + boff, &u.s.Bh[lb]);
            gload_lds16(Wl + boff, &u.s.Bl[lb]);
        }
        __syncthreads();                    // drains vmcnt: LDS tile ready

        short8 fah[4], fal[4], fbh[4], fbl[4];
        #pragma unroll
        for (int t = 0; t < 4; ++t) {
            const int ca = ((wm * 4 + t) * 4 + quad) * 16 + l16;
            fah[t] = *(const short8*)&u.s.Ah[ca * 8];
            fal[t] = *(const short8*)&u.s.Al[ca * 8];
            const int cb = ((wn * 4 + t) * 4 + quad) * 16 + l16;
            fbh[t] = *(const short8*)&u.s.Bh[cb * 8];
            fbl[t] = *(const short8*)&u.s.Bl[cb * 8];
        }
        #pragma unroll
        for (int im = 0; im < 4; ++im)
            #pragma unroll
            for (int in = 0; in < 4; ++in) {
                floatx4 a = acc[im][in];
                a = MFMA(fah[im], fbh[in], a, 0, 0, 0);
                a = MFMA(fal[im], fbh[in], a, 0, 0, 0);
                a = MFMA(fah[im], fbl[in], a, 0, 0, 0);
                acc[im][in] = a;
            }
    }

    // ---- epilogue ----
    const int which = n0 >> 9;       // 0=q 1=k 2=v (128-tiles never straddle)
    const int b    = m0 >> 10;
    const int tokb = m0 & 1023;
    if (which < 2) {
        unsigned short* HI = which ? Kh : Qh;
        unsigned short* LO = which ? Kl : Ql;
        // Q: fold SCALE * log2(e) = 0.125 * 1.4426950408889634
        const float sc = which ? 1.0f : 0.18033688011112042f;
        #pragma unroll
        for (int im = 0; im < 4; ++im) {
            const int tok = tokb + wm * 64 + im * 16 + quad * 4;
            #pragma unroll
            for (int in = 0; in < 4; ++in) {
                const int ncol = n0 + wn * 64 + in * 16 + l16;
                const int h = (ncol & 511) >> 6, d = ncol & 63;
                const size_t base = ((size_t)(b * Hh + h) * Nn + tok) * DHd + d;
                #pragma unroll
                for (int r = 0; r < 4; ++r) {
                    unsigned short hi, lo;
                    split_trunc(acc[im][in][r] * sc, hi, lo);
                    HI[base + (size_t)r * DHd] = hi;
                    LO[base + (size_t)r * DHd] = lo;
                }
            }
        }
    } else {
        // V: bf16 + transpose through LDS bounce -> Vt [bh][64][1024]
        __syncthreads();
        #pragma unroll
        for (int im = 0; im < 4; ++im)
            #pragma unroll
            for (int in = 0; in < 4; ++in)
                #pragma unroll
                for (int r = 0; r < 4; ++r)
                    u.bounce[wm * 64 + im * 16 + quad * 4 + r][wn * 64 + in * 16 + l16] =
                        bf16_rtn(acc[im][in][r]);
        __syncthreads();
        const int c = tid >> 1, tq = (tid & 1) * 64;
        const int h = ((n0 + c) & 511) >> 6, d = c & 63;
        unsigned short* vbase = Vt + ((size_t)(b * Hh + h) * DHd + d) * Nn + tokb;
        #pragma unroll
        for (int uu = 0; uu < 8; ++uu) {
            short8 v8;
            #pragma unroll
            for (int e = 0; e < 8; ++e)
                v8[e] = (short)u.bounce[tq + uu * 8 + e][c];
            *(short8*)&vbase[tq + uu * 8] = v8;
        }
    }
}

// ---------------------------------------------------------------------------
// MFMA flash attention. This round:
//  * XCD-chunked block swizzle (T1): 1-D grid 4096; XCD k owns bh [k*32,k*32+32),
//    i0-fastest => one bh's K/V (384KB) + decay slab stays L2-resident.
//  * shuffle-free softmax fast path: per-lane partial denominator (reduced
//    once at end); row-max shuffles only inside the rare rescale branch
//    (__all over per-lane maxima == test on reduced row max).
//  * pointer-bump staging (no per-iter 64-bit addr rebuild, no wrap mask;
//    final overshoot prefetch lands in adjacent workspace arrays, discarded).
// ---------------------------------------------------------------------------
__global__ __launch_bounds__(256) void attn_mfma_kernel(
    const unsigned short* __restrict__ Qh, const unsigned short* __restrict__ Ql,
    const unsigned short* __restrict__ Kh, const unsigned short* __restrict__ Kl,
    const unsigned short* __restrict__ Vt, const unsigned short* __restrict__ D16,
    unsigned short* __restrict__ AOh, unsigned short* __restrict__ AOl)
{
    __shared__ unsigned short Khs[32][72];   // [permuted j][d]
    __shared__ unsigned short Kls[32][72];
    __shared__ unsigned short Vts[64][40];   // [d][j]

    const int tid  = threadIdx.x;
    const int wave = tid >> 6;
    const int lane = tid & 63;
    const int quad = lane >> 4;
    const int l16  = lane & 15;
    // XCD-chunked swizzle: block lb -> XCD lb%8; XCD k processes wg in
    // [k*512, (k+1)*512) i.e. bh in [k*32, (k+1)*32), i0-fastest.
    const int lb   = blockIdx.x;
    const int wg   = (lb & 7) * 512 + (lb >> 3);
    const int bh   = wg >> 4;
    const int i0   = (wg & 15) << 6;
    const int b    = bh >> 3, h = bh & 7;
    const int iw   = i0 + wave * 16;

    // Q fragments (MFMA B operand: col = l16 = q-row, k = quad*8+e = d)
    const size_t qoff = ((size_t)bh * Nn + iw + l16) * DHd + quad * 8;
    const short8 qh0 = *(const short8*)(Qh + qoff);
    const short8 qh1 = *(const short8*)(Qh + qoff + 32);
    const short8 ql0 = *(const short8*)(Ql + qoff);
    const short8 ql1 = *(const short8*)(Ql + qoff + 32);

    floatx4 o_acc[4];
    #pragma unroll
    for (int nt = 0; nt < 4; ++nt) o_acc[nt] = (floatx4){0.f, 0.f, 0.f, 0.f};
    float m = -INFINITY;      // per-lane: row q = l16 (replicated across quads)
    float l = 0.f;            // PER-LANE partial denominator; reduced at end

    const int sj  = tid >> 3, sc2 = (tid & 7) * 8;       // K tiles: 32 x 64
    const int prow = ((sj >> 2) & 1) * 16 + ((sj >> 3) << 2) + (sj & 3);
    const int vd  = tid >> 2, vj8 = (tid & 3) * 8;       // Vt tile: 64 x 32
    const unsigned short* Dp = D16 + ((size_t)h * Nn + iw + l16) * Nn + quad * 8;

    // pointer-bump staging sources
    const unsigned short* kph = Kh + (size_t)bh * Nn * DHd + (size_t)sj * DHd + sc2;
    const unsigned short* kpl = Kl + (size_t)bh * Nn * DHd + (size_t)sj * DHd + sc2;
    const unsigned short* vpv = Vt + (size_t)bh * DHd * Nn + (size_t)vd * Nn + vj8;

    short8 pk_h = *(const short8*)kph; kph += 32 * DHd;
    short8 pk_l = *(const short8*)kpl; kpl += 32 * DHd;
    short8 pk_v = *(const short8*)vpv; vpv += 32;

    for (int j0 = 0; j0 < Nn; j0 += 32) {
        const short8 dc = *(const short8*)(Dp + j0);     // 8 fp16 decay values
        __syncthreads();
        *(short8*)&Khs[prow][sc2] = pk_h;
        *(short8*)&Kls[prow][sc2] = pk_l;
        *(short8*)&Vts[vd][vj8]   = pk_v;
        __syncthreads();
        {   // T14: issue next tile's loads now; latency hides under compute.
            // Last iteration overshoots into the next workspace array --
            // allocated memory, values discarded.
            pk_h = *(const short8*)kph; kph += 32 * DHd;
            pk_l = *(const short8*)kpl; kpl += 32 * DHd;
            pk_v = *(const short8*)vpv; vpv += 32;
        }

        // QK^T swapped: A = K (row = j), B = Q (col = q). 3-term split.
        floatx4 sacc[2];
        #pragma unroll
        for (int nh = 0; nh < 2; ++nh) {
            const int kr = nh * 16 + l16;
            short8 kh0 = *(const short8*)&Khs[kr][quad * 8];
            short8 kh1 = *(const short8*)&Khs[kr][32 + quad * 8];
            short8 kl0 = *(const short8*)&Kls[kr][quad * 8];
            short8 kl1 = *(const short8*)&Kls[kr][32 + quad * 8];
            floatx4 a = (floatx4){0.f, 0.f, 0.f, 0.f};
            a = MFMA(kh0, qh0, a, 0, 0, 0);
            a = MFMA(kh1, qh1, a, 0, 0, 0);
            a = MFMA(kl0, qh0, a, 0, 0, 0);
            a = MFMA(kl1, qh1, a, 0, 0, 0);
            a = MFMA(kh0, ql0, a, 0, 0, 0);
            a = MFMA(kh1, ql1, a, 0, 0, 0);
            sacc[nh] = a;
        }
        // lane holds S[q=l16][j0 + quad*8 + nh*4 + r]  (log2 domain)

        // lane-local max over this lane's 8 values (no cross-lane in fast path)
        float t = fmaxf(fmaxf(fmaxf(sacc[0][0], sacc[0][1]), fmaxf(sacc[0][2], sacc[0][3])),
                        fmaxf(fmaxf(sacc[1][0], sacc[1][1]), fmaxf(sacc[1][2], sacc[1][3])));

        // T13 defer-max: __all over per-lane maxima == test on full row max
        if (!__all(t <= m + 8.0f)) {
            t = fmaxf(t, __shfl_xor(t, 16));
            t = fmaxf(t, __shfl_xor(t, 32));
            const float nm = fmaxf(m, t);
            const float fac = EXP2(m - nm);
            m = nm;
            l *= fac;
            float fr[4];
            #pragma unroll
            for (int r = 0; r < 4; ++r) fr[r] = __shfl(fac, quad * 4 + r);
            #pragma unroll
            for (int nt = 0; nt < 4; ++nt) {
                floatx4 t4 = o_acc[nt];
                t4[0] *= fr[0]; t4[1] *= fr[1]; t4[2] *= fr[2]; t4[3] *= fr[3];
                o_acc[nt] = t4;
            }
        }

        float p[8];
        #pragma unroll
        for (int e = 0; e < 4; ++e) p[e]     = EXP2(sacc[0][e] - m);
        #pragma unroll
        for (int e = 0; e < 4; ++e) p[4 + e] = EXP2(sacc[1][e] - m);
        l += ((p[0] + p[1]) + (p[2] + p[3])) + ((p[4] + p[5]) + (p[6] + p[7]));

        // P * decay -> bf16 A-fragment, fully in-register
        union { int i4[4]; short8 s8; } pfu;
        #pragma unroll
        for (int e = 0; e < 4; ++e) {
            const float d0 = __half2float(__ushort_as_half((unsigned short)dc[2 * e]));
            const float d1 = __half2float(__ushort_as_half((unsigned short)dc[2 * e + 1]));
            pfu.i4[e] = cvt_pk_bf16(p[2 * e] * d0, p[2 * e + 1] * d1);
        }
        #pragma unroll
        for (int nt = 0; nt < 4; ++nt) {
            short8 vf = *(const short8*)&Vts[nt * 16 + l16][quad * 8];
            o_acc[nt] = MFMA(pfu.s8, vf, o_acc[nt], 0, 0, 0);
        }
    }

    // reduce the per-lane partial denominator across quads (once)
    float lsum = l;
    lsum += __shfl_xor(lsum, 16);
    lsum += __shfl_xor(lsum, 32);
    const float inv = 1.f / lsum;
    float ir[4];
    #pragma unroll
    for (int r = 0; r < 4; ++r) ir[r] = __shfl(inv, quad * 4 + r);
    const size_t aob = ((size_t)b * Nn + i0 + wave * 16) * DIMc + h * DHd;
    #pragma unroll
    for (int nt = 0; nt < 4; ++nt)
        #pragma unroll
        for (int r = 0; r < 4; ++r) {
            unsigned short hi, lo;
            split_trunc(o_acc[nt][r] * ir[r], hi, lo);
            const size_t off = aob + (size_t)(quad * 4 + r) * DIMc + nt * 16 + l16;
            AOh[off] = hi;
            AOl[off] = lo;
        }
}

// ---------------------------------------------------------------------------
// GEMM2 (MFMA, 3-term split): out = AO @ W_out + b_out ; staging pure
// global_load_lds width=16 (operands already bf16 hi/lo in global).
// ---------------------------------------------------------------------------
__global__ __launch_bounds__(256) void gemm_out_mfma(
    const unsigned short* __restrict__ Agh, const unsigned short* __restrict__ Agl,
    const unsigned short* __restrict__ Wh, const unsigned short* __restrict__ Wl,
    const float* __restrict__ bias, float* __restrict__ C)
{
    __shared__ struct { unsigned short Ah[4096], Al[4096], Bh[4096], Bl[4096]; } s;

    const int tid  = threadIdx.x;
    const int w    = tid >> 6;
    const int lane = tid & 63;
    const int quad = lane >> 4;
    const int l16  = lane & 15;
    const int n0 = blockIdx.x * 128;
    const int m0 = blockIdx.y * 128;
    const int wm = w >> 1, wn = w & 1;

    floatx4 acc[4][4];
    #pragma unroll
    for (int im = 0; im < 4; ++im)
        #pragma unroll
        for (int in = 0; in < 4; ++in)
            acc[im][in] = (floatx4){0.f, 0.f, 0.f, 0.f};

    for (int k0 = 0; k0 < GK; k0 += 32) {
        __syncthreads();
        #pragma unroll
        for (int i = 0; i < 2; ++i) {
            const int row = i * 64 + w * 16 + l16;
            const size_t aoff = (size_t)(m0 + row) * GK + k0 + quad * 8;
            const size_t boff = (size_t)(n0 + row) * GK + k0 + quad * 8;
            const int lb = (i * 4 + w) * 512;
            gload_lds16(Agh + aoff, &s.Ah[lb]);
            gload_lds16(Agl + aoff, &s.Al[lb]);
            gload_lds16(Wh + boff, &s.Bh[lb]);
            gload_lds16(Wl + boff, &s.Bl[lb]);
        }
        __syncthreads();

        short8 fah[4], fal[4], fbh[4], fbl[4];
        #pragma unroll
        for (int t = 0; t < 4; ++t) {
            const int ca = ((wm * 4 + t) * 4 + quad) * 16 + l16;
            fah[t] = *(const short8*)&s.Ah[ca * 8];
            fal[t] = *(const short8*)&s.Al[ca * 8];
            const int cb = ((wn * 4 + t) * 4 + quad) * 16 + l16;
            fbh[t] = *(const short8*)&s.Bh[cb * 8];
            fbl[t] = *(const short8*)&s.Bl[cb * 8];
        }
        #pragma unroll
        for (int im = 0; im < 4; ++im)
            #pragma unroll
            for (int in = 0; in < 4; ++in) {
                floatx4 a = acc[im][in];
                a = MFMA(fah[im], fbh[in], a, 0, 0, 0);
                a = MFMA(fal[im], fbh[in], a, 0, 0, 0);
                a = MFMA(fah[im], fbl[in], a, 0, 0, 0);
                acc[im][in] = a;
            }
    }

    float biasv[4];
    #pragma unroll
    for (int in = 0; in < 4; ++in) biasv[in] = bias[n0 + wn * 64 + in * 16 + l16];
    #pragma unroll
    for (int im = 0; im < 4; ++im)
        #pragma unroll
        for (int in = 0; in < 4; ++in) {
            const int mrow = m0 + wm * 64 + im * 16 + quad * 4;
            const int ncol = n0 + wn * 64 + in * 16 + l16;
            #pragma unroll
            for (int r = 0; r < 4; ++r)
                C[(size_t)(mrow + r) * DIMc + ncol] = acc[im][in][r] + biasv[in];
        }
}

// ---------------------------------------------------------------------------
extern "C" void kernel_launch(void* const* d_in, const int* in_sizes, int n_in,
                              void* d_out, int out_size, void* d_ws, size_t ws_size,
                              hipStream_t stream)
{
    const float* x     = (const float*)d_in[0];
    const float* Wqkv  = (const float*)d_in[1];
    const float* Wout  = (const float*)d_in[2];
    const float* bout  = (const float*)d_in[3];
    const float* decay = (const float*)d_in[4];

    const size_t E = (size_t)32768 * 512;   // 16,777,216
    unsigned short* p = (unsigned short*)d_ws;
    unsigned short* Qh  = p; p += E;
    unsigned short* Ql  = p; p += E;
    unsigned short* Kh  = p; p += E;
    unsigned short* Kl  = p; p += E;
    unsigned short* Vt  = p; p += E;
    unsigned short* AOh = p; p += E;
    unsigned short* AOl = p; p += E;
    unsigned short* Wqh = p; p += 786432;
    unsigned short* Wql = p; p += 786432;
    unsigned short* Woh = p; p += 262144;
    unsigned short* Wol = p; p += 262144;
    unsigned short* D16 = p;               // 8,388,608 halves
    // total: ~244 MiB. Xh/Xl ALIAS AOh/AOl: X's split is dead before attn
    // writes AO (stream-serialized), so no extra workspace.
    unsigned short* Xh = AOh;
    unsigned short* Xl = AOl;

    transpose_split_kernel<<<dim3(48, 16), 256, 0, stream>>>(Wqkv, 512, 1536, Wqh, Wql);
    transpose_split_kernel<<<dim3(16, 16), 256, 0, stream>>>(Wout, 512, 512, Woh, Wol);
    decay_to_half_kernel<<<dim3(8192), 256, 0, stream>>>(decay, D16);
    split_x_kernel<<<dim3(8192), 256, 0, stream>>>(x, Xh, Xl);
    gemm_qkv_mfma<<<dim3(12, 256), 256, 0, stream>>>(Xh, Xl, Wqh, Wql, Qh, Ql, Kh, Kl, Vt);
    attn_mfma_kernel<<<dim3(4096), 256, 0, stream>>>(Qh, Ql, Kh, Kl, Vt, D16, AOh, AOl);
    gemm_out_mfma<<<dim3(4, 256), 256, 0, stream>>>(AOh, AOl, Woh, Wol, bout, (float*)d_out);
}

// Round 4
// 510.937 us; speedup vs baseline: 1.3584x; 1.0465x over previous
//
#include <hip/hip_runtime.h>
#include <hip/hip_fp16.h>
#include <math.h>

// Problem constants
#define Bb 32
#define Nn 1024
#define DIMc 512
#define Hh 8
#define DHd 64
#define GK 512          // K for both projection GEMMs

typedef __attribute__((ext_vector_type(8))) short short8;   // 8 bf16 (4 VGPRs)
typedef __attribute__((ext_vector_type(4))) float floatx4;  // MFMA 16x16 acc

#define MFMA __builtin_amdgcn_mfma_f32_16x16x32_bf16

#if __has_builtin(__builtin_amdgcn_exp2f)
#define EXP2(x) __builtin_amdgcn_exp2f(x)
#else
#define EXP2(x) __expf((x) * 0.6931471805599453f)
#endif

__device__ __forceinline__ unsigned short bf16_rtn(float f) {
    unsigned int u = __float_as_uint(f);
    u += 0x7FFFu + ((u >> 16) & 1u);     // round-to-nearest-even
    return (unsigned short)(u >> 16);
}
__device__ __forceinline__ float bf16_to_f32(unsigned short h) {
    return __uint_as_float(((unsigned int)h) << 16);
}
// Truncation split: f == hi + lo exactly in fp32 (Dekker-style); lo then
// truncated to bf16 (residual of residual ~2^-16 rel -- below noise floor).
__device__ __forceinline__ void split_trunc(float f, unsigned short& hi, unsigned short& lo) {
    unsigned int u = __float_as_uint(f) & 0xFFFF0000u;
    hi = (unsigned short)(u >> 16);
    float rest = f - __uint_as_float(u);
    lo = (unsigned short)(__float_as_uint(rest) >> 16);
}
// pack 2 fp32 -> 2 bf16 in one dword (lo -> bits 0..15, hi -> bits 16..31)
__device__ __forceinline__ int cvt_pk_bf16(float lo, float hi) {
    int r;
    asm("v_cvt_pk_bf16_f32 %0, %1, %2" : "=v"(r) : "v"(lo), "v"(hi));
    return r;
}
// async global->LDS, 16 bytes per lane; LDS dest = wave-uniform base + lane*16
__device__ __forceinline__ void gload_lds16(const unsigned short* g, unsigned short* l) {
    __builtin_amdgcn_global_load_lds(
        (const __attribute__((address_space(1))) unsigned int*)g,
        (__attribute__((address_space(3))) unsigned int*)l,
        16, 0, 0);
}

// ---------------------------------------------------------------------------
// Prep 1: transpose + split fp32 weight [K][N] -> hi/lo bf16 [N][K]
// ---------------------------------------------------------------------------
__global__ __launch_bounds__(256) void transpose_split_kernel(
    const float* __restrict__ src, int K, int N,
    unsigned short* __restrict__ dh, unsigned short* __restrict__ dl)
{
    __shared__ float T[32][33];
    const int tid = threadIdx.x;
    const int c = tid & 31, r0 = tid >> 5;
    const int nb = blockIdx.x * 32, kb = blockIdx.y * 32;
    #pragma unroll
    for (int i = 0; i < 4; ++i)
        T[r0 + i * 8][c] = src[(size_t)(kb + r0 + i * 8) * N + nb + c];
    __syncthreads();
    #pragma unroll
    for (int i = 0; i < 4; ++i) {
        int n = r0 + i * 8;
        unsigned short hi, lo;
        split_trunc(T[c][n], hi, lo);
        size_t off = (size_t)(nb + n) * K + kb + c;
        dh[off] = hi;
        dl[off] = lo;
    }
}

// ---------------------------------------------------------------------------
// Prep 2: decay fp32 -> fp16 (post-softmax multiplier; fp16 rel err ~5e-4)
// ---------------------------------------------------------------------------
__global__ __launch_bounds__(256) void decay_to_half_kernel(
    const float* __restrict__ D, unsigned short* __restrict__ D16)
{
    size_t i = ((size_t)blockIdx.x * 256 + threadIdx.x) * 4;
    float4 v = *(const float4*)(D + i);
    ushort4 o;
    o.x = __half_as_ushort(__float2half(v.x));
    o.y = __half_as_ushort(__float2half(v.y));
    o.z = __half_as_ushort(__float2half(v.z));
    o.w = __half_as_ushort(__float2half(v.w));
    *(ushort4*)(D16 + i) = o;
}

// ---------------------------------------------------------------------------
// Prep 3: split fp32 activations X -> hi/lo bf16 (done ONCE).
// Xh/Xl alias AOh/AOl (dead until attn writes AO).
// ---------------------------------------------------------------------------
__global__ __launch_bounds__(256) void split_x_kernel(
    const float* __restrict__ X,
    unsigned short* __restrict__ Xh, unsigned short* __restrict__ Xl)
{
    size_t i = ((size_t)blockIdx.x * 256 + threadIdx.x) * 8;
    float4 a = *(const float4*)(X + i);
    float4 b = *(const float4*)(X + i + 4);
    float f[8] = {a.x, a.y, a.z, a.w, b.x, b.y, b.z, b.w};
    short8 hi, lo;
    #pragma unroll
    for (int e = 0; e < 8; ++e) {
        unsigned short h_, l_;
        split_trunc(f[e], h_, l_);
        hi[e] = (short)h_;
        lo[e] = (short)l_;
    }
    *(short8*)(Xh + i) = hi;
    *(short8*)(Xl + i) = lo;
}

// ---------------------------------------------------------------------------
// GEMM1 (MFMA, 3-term split): qkv = x @ W_qkv
// 2-phase double-buffered staging (T3-lite): tile t+1 is issued via
// global_load_lds BEFORE computing tile t; ONE __syncthreads per K-step.
// Its implicit vmcnt(0) waits on loads that are a full compute-phase old
// (latency hidden); its lgkmcnt(0) guarantees all waves finished reading
// the buffer the next STAGE overwrites.
// ---------------------------------------------------------------------------
__global__ __launch_bounds__(256) void gemm_qkv_mfma(
    const unsigned short* __restrict__ Xh, const unsigned short* __restrict__ Xl,
    const unsigned short* __restrict__ Wh, const unsigned short* __restrict__ Wl,
    unsigned short* __restrict__ Qh, unsigned short* __restrict__ Ql,
    unsigned short* __restrict__ Kh, unsigned short* __restrict__ Kl,
    unsigned short* __restrict__ Vt)
{
    __shared__ union {
        struct { unsigned short Ah[2][4096], Al[2][4096], Bh[2][4096], Bl[2][4096]; } s;
        unsigned short bounce[128][136];   // V-transpose bounce (epilogue only)
    } u;

    const int tid  = threadIdx.x;
    const int w    = tid >> 6;
    const int lane = tid & 63;
    const int quad = lane >> 4;
    const int l16  = lane & 15;
    const int n0 = blockIdx.x * 128;
    const int m0 = blockIdx.y * 128;
    const int wm = w >> 1, wn = w & 1;

    floatx4 acc[4][4];
    #pragma unroll
    for (int im = 0; im < 4; ++im)
        #pragma unroll
        for (int in = 0; in < 4; ++in)
            acc[im][in] = (floatx4){0.f, 0.f, 0.f, 0.f};

    // prologue: stage K-tile 0 into buffer 0
    #pragma unroll
    for (int i = 0; i < 2; ++i) {
        const int row = i * 64 + w * 16 + l16;
        const size_t aoff = (size_t)(m0 + row) * GK + quad * 8;
        const size_t boff = (size_t)(n0 + row) * GK + quad * 8;
        const int lb = (i * 4 + w) * 512;
        gload_lds16(Xh + aoff, &u.s.Ah[0][lb]);
        gload_lds16(Xl + aoff, &u.s.Al[0][lb]);
        gload_lds16(Wh + boff, &u.s.Bh[0][lb]);
        gload_lds16(Wl + boff, &u.s.Bl[0][lb]);
    }

    int cur = 0;
    for (int k0 = 0; k0 < GK; k0 += 32) {
        __syncthreads();   // vmcnt(0): buf[cur] ready; lgkm: buf[cur^1] free
        if (k0 + 32 < GK) {
            const int kn = k0 + 32;
            #pragma unroll
            for (int i = 0; i < 2; ++i) {
                const int row = i * 64 + w * 16 + l16;
                const size_t aoff = (size_t)(m0 + row) * GK + kn + quad * 8;
                const size_t boff = (size_t)(n0 + row) * GK + kn + quad * 8;
                const int lb = (i * 4 + w) * 512;
                gload_lds16(Xh + aoff, &u.s.Ah[cur ^ 1][lb]);
                gload_lds16(Xl + aoff, &u.s.Al[cur ^ 1][lb]);
                gload_lds16(Wh + boff, &u.s.Bh[cur ^ 1][lb]);
                gload_lds16(Wl + boff, &u.s.Bl[cur ^ 1][lb]);
            }
        }

        short8 fah[4], fal[4], fbh[4], fbl[4];
        #pragma unroll
        for (int t = 0; t < 4; ++t) {
            const int ca = ((wm * 4 + t) * 4 + quad) * 16 + l16;
            fah[t] = *(const short8*)&u.s.Ah[cur][ca * 8];
            fal[t] = *(const short8*)&u.s.Al[cur][ca * 8];
            const int cb = ((wn * 4 + t) * 4 + quad) * 16 + l16;
            fbh[t] = *(const short8*)&u.s.Bh[cur][cb * 8];
            fbl[t] = *(const short8*)&u.s.Bl[cur][cb * 8];
        }
        #pragma unroll
        for (int im = 0; im < 4; ++im)
            #pragma unroll
            for (int in = 0; in < 4; ++in) {
                floatx4 a = acc[im][in];
                a = MFMA(fah[im], fbh[in], a, 0, 0, 0);
                a = MFMA(fal[im], fbh[in], a, 0, 0, 0);
                a = MFMA(fah[im], fbl[in], a, 0, 0, 0);
                acc[im][in] = a;
            }
        cur ^= 1;
    }

    // ---- epilogue ----
    const int which = n0 >> 9;       // 0=q 1=k 2=v (128-tiles never straddle)
    const int b    = m0 >> 10;
    const int tokb = m0 & 1023;
    if (which < 2) {
        unsigned short* HI = which ? Kh : Qh;
        unsigned short* LO = which ? Kl : Ql;
        // Q: fold SCALE * log2(e) = 0.125 * 1.4426950408889634
        const float sc = which ? 1.0f : 0.18033688011112042f;
        #pragma unroll
        for (int im = 0; im < 4; ++im) {
            const int tok = tokb + wm * 64 + im * 16 + quad * 4;
            #pragma unroll
            for (int in = 0; in < 4; ++in) {
                const int ncol = n0 + wn * 64 + in * 16 + l16;
                const int h = (ncol & 511) >> 6, d = ncol & 63;
                const size_t base = ((size_t)(b * Hh + h) * Nn + tok) * DHd + d;
                #pragma unroll
                for (int r = 0; r < 4; ++r) {
                    unsigned short hi, lo;
                    split_trunc(acc[im][in][r] * sc, hi, lo);
                    HI[base + (size_t)r * DHd] = hi;
                    LO[base + (size_t)r * DHd] = lo;
                }
            }
        }
    } else {
        // V: bf16 + transpose through LDS bounce -> Vt [bh][64][1024]
        __syncthreads();
        #pragma unroll
        for (int im = 0; im < 4; ++im)
            #pragma unroll
            for (int in = 0; in < 4; ++in)
                #pragma unroll
                for (int r = 0; r < 4; ++r)
                    u.bounce[wm * 64 + im * 16 + quad * 4 + r][wn * 64 + in * 16 + l16] =
                        bf16_rtn(acc[im][in][r]);
        __syncthreads();
        const int c = tid >> 1, tq = (tid & 1) * 64;
        const int h = ((n0 + c) & 511) >> 6, d = c & 63;
        unsigned short* vbase = Vt + ((size_t)(b * Hh + h) * DHd + d) * Nn + tokb;
        #pragma unroll
        for (int uu = 0; uu < 8; ++uu) {
            short8 v8;
            #pragma unroll
            for (int e = 0; e < 8; ++e)
                v8[e] = (short)u.bounce[tq + uu * 8 + e][c];
            *(short8*)&vbase[tq + uu * 8] = v8;
        }
    }
}

// ---------------------------------------------------------------------------
// MFMA flash attention (unchanged this round): XCD-chunked swizzle, swapped
// QK^T, shuffle-free softmax fast path, in-register P, pointer-bump prefetch.
// ---------------------------------------------------------------------------
__global__ __launch_bounds__(256) void attn_mfma_kernel(
    const unsigned short* __restrict__ Qh, const unsigned short* __restrict__ Ql,
    const unsigned short* __restrict__ Kh, const unsigned short* __restrict__ Kl,
    const unsigned short* __restrict__ Vt, const unsigned short* __restrict__ D16,
    unsigned short* __restrict__ AOh, unsigned short* __restrict__ AOl)
{
    __shared__ unsigned short Khs[32][72];   // [permuted j][d]
    __shared__ unsigned short Kls[32][72];
    __shared__ unsigned short Vts[64][40];   // [d][j]

    const int tid  = threadIdx.x;
    const int wave = tid >> 6;
    const int lane = tid & 63;
    const int quad = lane >> 4;
    const int l16  = lane & 15;
    const int lb   = blockIdx.x;
    const int wg   = (lb & 7) * 512 + (lb >> 3);
    const int bh   = wg >> 4;
    const int i0   = (wg & 15) << 6;
    const int b    = bh >> 3, h = bh & 7;
    const int iw   = i0 + wave * 16;

    const size_t qoff = ((size_t)bh * Nn + iw + l16) * DHd + quad * 8;
    const short8 qh0 = *(const short8*)(Qh + qoff);
    const short8 qh1 = *(const short8*)(Qh + qoff + 32);
    const short8 ql0 = *(const short8*)(Ql + qoff);
    const short8 ql1 = *(const short8*)(Ql + qoff + 32);

    floatx4 o_acc[4];
    #pragma unroll
    for (int nt = 0; nt < 4; ++nt) o_acc[nt] = (floatx4){0.f, 0.f, 0.f, 0.f};
    float m = -INFINITY;      // per-lane: row q = l16 (replicated across quads)
    float l = 0.f;            // PER-LANE partial denominator; reduced at end

    const int sj  = tid >> 3, sc2 = (tid & 7) * 8;       // K tiles: 32 x 64
    const int prow = ((sj >> 2) & 1) * 16 + ((sj >> 3) << 2) + (sj & 3);
    const int vd  = tid >> 2, vj8 = (tid & 3) * 8;       // Vt tile: 64 x 32
    const unsigned short* Dp = D16 + ((size_t)h * Nn + iw + l16) * Nn + quad * 8;

    const unsigned short* kph = Kh + (size_t)bh * Nn * DHd + (size_t)sj * DHd + sc2;
    const unsigned short* kpl = Kl + (size_t)bh * Nn * DHd + (size_t)sj * DHd + sc2;
    const unsigned short* vpv = Vt + (size_t)bh * DHd * Nn + (size_t)vd * Nn + vj8;

    short8 pk_h = *(const short8*)kph; kph += 32 * DHd;
    short8 pk_l = *(const short8*)kpl; kpl += 32 * DHd;
    short8 pk_v = *(const short8*)vpv; vpv += 32;

    for (int j0 = 0; j0 < Nn; j0 += 32) {
        const short8 dc = *(const short8*)(Dp + j0);     // 8 fp16 decay values
        __syncthreads();
        *(short8*)&Khs[prow][sc2] = pk_h;
        *(short8*)&Kls[prow][sc2] = pk_l;
        *(short8*)&Vts[vd][vj8]   = pk_v;
        __syncthreads();
        {   // prefetch next tile (overshoot lands in adjacent workspace, discarded)
            pk_h = *(const short8*)kph; kph += 32 * DHd;
            pk_l = *(const short8*)kpl; kpl += 32 * DHd;
            pk_v = *(const short8*)vpv; vpv += 32;
        }

        floatx4 sacc[2];
        #pragma unroll
        for (int nh = 0; nh < 2; ++nh) {
            const int kr = nh * 16 + l16;
            short8 kh0 = *(const short8*)&Khs[kr][quad * 8];
            short8 kh1 = *(const short8*)&Khs[kr][32 + quad * 8];
            short8 kl0 = *(const short8*)&Kls[kr][quad * 8];
            short8 kl1 = *(const short8*)&Kls[kr][32 + quad * 8];
            floatx4 a = (floatx4){0.f, 0.f, 0.f, 0.f};
            a = MFMA(kh0, qh0, a, 0, 0, 0);
            a = MFMA(kh1, qh1, a, 0, 0, 0);
            a = MFMA(kl0, qh0, a, 0, 0, 0);
            a = MFMA(kl1, qh1, a, 0, 0, 0);
            a = MFMA(kh0, ql0, a, 0, 0, 0);
            a = MFMA(kh1, ql1, a, 0, 0, 0);
            sacc[nh] = a;
        }

        float t = fmaxf(fmaxf(fmaxf(sacc[0][0], sacc[0][1]), fmaxf(sacc[0][2], sacc[0][3])),
                        fmaxf(fmaxf(sacc[1][0], sacc[1][1]), fmaxf(sacc[1][2], sacc[1][3])));

        if (!__all(t <= m + 8.0f)) {
            t = fmaxf(t, __shfl_xor(t, 16));
            t = fmaxf(t, __shfl_xor(t, 32));
            const float nm = fmaxf(m, t);
            const float fac = EXP2(m - nm);
            m = nm;
            l *= fac;
            float fr[4];
            #pragma unroll
            for (int r = 0; r < 4; ++r) fr[r] = __shfl(fac, quad * 4 + r);
            #pragma unroll
            for (int nt = 0; nt < 4; ++nt) {
                floatx4 t4 = o_acc[nt];
                t4[0] *= fr[0]; t4[1] *= fr[1]; t4[2] *= fr[2]; t4[3] *= fr[3];
                o_acc[nt] = t4;
            }
        }

        float p[8];
        #pragma unroll
        for (int e = 0; e < 4; ++e) p[e]     = EXP2(sacc[0][e] - m);
        #pragma unroll
        for (int e = 0; e < 4; ++e) p[4 + e] = EXP2(sacc[1][e] - m);
        l += ((p[0] + p[1]) + (p[2] + p[3])) + ((p[4] + p[5]) + (p[6] + p[7]));

        union { int i4[4]; short8 s8; } pfu;
        #pragma unroll
        for (int e = 0; e < 4; ++e) {
            const float d0 = __half2float(__ushort_as_half((unsigned short)dc[2 * e]));
            const float d1 = __half2float(__ushort_as_half((unsigned short)dc[2 * e + 1]));
            pfu.i4[e] = cvt_pk_bf16(p[2 * e] * d0, p[2 * e + 1] * d1);
        }
        #pragma unroll
        for (int nt = 0; nt < 4; ++nt) {
            short8 vf = *(const short8*)&Vts[nt * 16 + l16][quad * 8];
            o_acc[nt] = MFMA(pfu.s8, vf, o_acc[nt], 0, 0, 0);
        }
    }

    float lsum = l;
    lsum += __shfl_xor(lsum, 16);
    lsum += __shfl_xor(lsum, 32);
    const float inv = 1.f / lsum;
    float ir[4];
    #pragma unroll
    for (int r = 0; r < 4; ++r) ir[r] = __shfl(inv, quad * 4 + r);
    const size_t aob = ((size_t)b * Nn + i0 + wave * 16) * DIMc + h * DHd;
    #pragma unroll
    for (int nt = 0; nt < 4; ++nt)
        #pragma unroll
        for (int r = 0; r < 4; ++r) {
            unsigned short hi, lo;
            split_trunc(o_acc[nt][r] * ir[r], hi, lo);
            const size_t off = aob + (size_t)(quad * 4 + r) * DIMc + nt * 16 + l16;
            AOh[off] = hi;
            AOl[off] = lo;
        }
}

// ---------------------------------------------------------------------------
// GEMM2 (MFMA, 3-term split): out = AO @ W_out + b_out ; 2-phase
// double-buffered global_load_lds staging, one barrier per K-step.
// ---------------------------------------------------------------------------
__global__ __launch_bounds__(256) void gemm_out_mfma(
    const unsigned short* __restrict__ Agh, const unsigned short* __restrict__ Agl,
    const unsigned short* __restrict__ Wh, const unsigned short* __restrict__ Wl,
    const float* __restrict__ bias, float* __restrict__ C)
{
    __shared__ struct { unsigned short Ah[2][4096], Al[2][4096], Bh[2][4096], Bl[2][4096]; } s;

    const int tid  = threadIdx.x;
    const int w    = tid >> 6;
    const int lane = tid & 63;
    const int quad = lane >> 4;
    const int l16  = lane & 15;
    const int n0 = blockIdx.x * 128;
    const int m0 = blockIdx.y * 128;
    const int wm = w >> 1, wn = w & 1;

    floatx4 acc[4][4];
    #pragma unroll
    for (int im = 0; im < 4; ++im)
        #pragma unroll
        for (int in = 0; in < 4; ++in)
            acc[im][in] = (floatx4){0.f, 0.f, 0.f, 0.f};

    #pragma unroll
    for (int i = 0; i < 2; ++i) {
        const int row = i * 64 + w * 16 + l16;
        const size_t aoff = (size_t)(m0 + row) * GK + quad * 8;
        const size_t boff = (size_t)(n0 + row) * GK + quad * 8;
        const int lb = (i * 4 + w) * 512;
        gload_lds16(Agh + aoff, &s.Ah[0][lb]);
        gload_lds16(Agl + aoff, &s.Al[0][lb]);
        gload_lds16(Wh + boff, &s.Bh[0][lb]);
        gload_lds16(Wl + boff, &s.Bl[0][lb]);
    }

    int cur = 0;
    for (int k0 = 0; k0 < GK; k0 += 32) {
        __syncthreads();
        if (k0 + 32 < GK) {
            const int kn = k0 + 32;
            #pragma unroll
            for (int i = 0; i < 2; ++i) {
                const int row = i * 64 + w * 16 + l16;
                const size_t aoff = (size_t)(m0 + row) * GK + kn + quad * 8;
                const size_t boff = (size_t)(n0 + row) * GK + kn + quad * 8;
                const int lb = (i * 4 + w) * 512;
                gload_lds16(Agh + aoff, &s.Ah[cur ^ 1][lb]);
                gload_lds16(Agl + aoff, &s.Al[cur ^ 1][lb]);
                gload_lds16(Wh + boff, &s.Bh[cur ^ 1][lb]);
                gload_lds16(Wl + boff, &s.Bl[cur ^ 1][lb]);
            }
        }

        short8 fah[4], fal[4], fbh[4], fbl[4];
        #pragma unroll
        for (int t = 0; t < 4; ++t) {
            const int ca = ((wm * 4 + t) * 4 + quad) * 16 + l16;
            fah[t] = *(const short8*)&s.Ah[cur][ca * 8];
            fal[t] = *(const short8*)&s.Al[cur][ca * 8];
            const int cb = ((wn * 4 + t) * 4 + quad) * 16 + l16;
            fbh[t] = *(const short8*)&s.Bh[cur][cb * 8];
            fbl[t] = *(const short8*)&s.Bl[cur][cb * 8];
        }
        #pragma unroll
        for (int im = 0; im < 4; ++im)
            #pragma unroll
            for (int in = 0; in < 4; ++in) {
                floatx4 a = acc[im][in];
                a = MFMA(fah[im], fbh[in], a, 0, 0, 0);
                a = MFMA(fal[im], fbh[in], a, 0, 0, 0);
                a = MFMA(fah[im], fbl[in], a, 0, 0, 0);
                acc[im][in] = a;
            }
        cur ^= 1;
    }

    float biasv[4];
    #pragma unroll
    for (int in = 0; in < 4; ++in) biasv[in] = bias[n0 + wn * 64 + in * 16 + l16];
    #pragma unroll
    for (int im = 0; im < 4; ++im)
        #pragma unroll
        for (int in = 0; in < 4; ++in) {
            const int mrow = m0 + wm * 64 + im * 16 + quad * 4;
            const int ncol = n0 + wn * 64 + in * 16 + l16;
            #pragma unroll
            for (int r = 0; r < 4; ++r)
                C[(size_t)(mrow + r) * DIMc + ncol] = acc[im][in][r] + biasv[in];
        }
}

// ---------------------------------------------------------------------------
extern "C" void kernel_launch(void* const* d_in, const int* in_sizes, int n_in,
                              void* d_out, int out_size, void* d_ws, size_t ws_size,
                              hipStream_t stream)
{
    const float* x     = (const float*)d_in[0];
    const float* Wqkv  = (const float*)d_in[1];
    const float* Wout  = (const float*)d_in[2];
    const float* bout  = (const float*)d_in[3];
    const float* decay = (const float*)d_in[4];

    const size_t E = (size_t)32768 * 512;   // 16,777,216
    unsigned short* p = (unsigned short*)d_ws;
    unsigned short* Qh  = p; p += E;
    unsigned short* Ql  = p; p += E;
    unsigned short* Kh  = p; p += E;
    unsigned short* Kl  = p; p += E;
    unsigned short* Vt  = p; p += E;
    unsigned short* AOh = p; p += E;
    unsigned short* AOl = p; p += E;
    unsigned short* Wqh = p; p += 786432;
    unsigned short* Wql = p; p += 786432;
    unsigned short* Woh = p; p += 262144;
    unsigned short* Wol = p; p += 262144;
    unsigned short* D16 = p;               // 8,388,608 halves
    // total: ~244 MiB. Xh/Xl ALIAS AOh/AOl: X's split is dead before attn
    // writes AO (stream-serialized), so no extra workspace.
    unsigned short* Xh = AOh;
    unsigned short* Xl = AOl;

    transpose_split_kernel<<<dim3(48, 16), 256, 0, stream>>>(Wqkv, 512, 1536, Wqh, Wql);
    transpose_split_kernel<<<dim3(16, 16), 256, 0, stream>>>(Wout, 512, 512, Woh, Wol);
    decay_to_half_kernel<<<dim3(8192), 256, 0, stream>>>(decay, D16);
    split_x_kernel<<<dim3(8192), 256, 0, stream>>>(x, Xh, Xl);
    gemm_qkv_mfma<<<dim3(12, 256), 256, 0, stream>>>(Xh, Xl, Wqh, Wql, Qh, Ql, Kh, Kl, Vt);
    attn_mfma_kernel<<<dim3(4096), 256, 0, stream>>>(Qh, Ql, Kh, Kl, Vt, D16, AOh, AOl);
    gemm_out_mfma<<<dim3(4, 256), 256, 0, stream>>>(AOh, AOl, Woh, Wol, bout, (float*)d_out);
}

// Round 6
// 390.221 us; speedup vs baseline: 1.7786x; 1.3094x over previous
//
#include <hip/hip_runtime.h>
#include <hip/hip_fp16.h>
#include <math.h>

// Problem constants
#define Bb 32
#define Nn 1024
#define DIMc 512
#define Hh 8
#define DHd 64
#define GK 512          // K for both projection GEMMs

typedef __attribute__((ext_vector_type(8))) short short8;     // 16B of 16-bit elems
typedef __attribute__((ext_vector_type(8))) _Float16 half8;   // MFMA f16 A/B frag
typedef __attribute__((ext_vector_type(2))) __fp16 fp16x2;    // cvt_pkrtz result
typedef __attribute__((ext_vector_type(4))) float floatx4;    // MFMA 16x16 acc

#define MFMA16 __builtin_amdgcn_mfma_f32_16x16x32_f16

#if __has_builtin(__builtin_amdgcn_exp2f)
#define EXP2(x) __builtin_amdgcn_exp2f(x)
#else
#define EXP2(x) __expf((x) * 0.6931471805599453f)
#endif

__device__ __forceinline__ unsigned short f16_bits(float f) {
    return __half_as_ushort(__float2half(f));   // RTN
}
// bf16-truncation split of fp32 weight: hi = bf16-trunc value (exactly
// representable in fp16 for normal range), rest = f - hi (<= 2^-7 rel,
// fp16-normal for |f| >= ~8e-3) -> W represented to ~2^-18 as fp16 pair.
__device__ __forceinline__ void split_w_f16(float f, unsigned short& hi, unsigned short& lo) {
    float hf = __uint_as_float(__float_as_uint(f) & 0xFFFF0000u);
    hi = f16_bits(hf);
    lo = f16_bits(f - hf);
}
// pack 2 fp32 -> 2 fp16 (RTZ) in one dword
__device__ __forceinline__ int cvt_pk_f16(float a, float b) {
    fp16x2 r = __builtin_amdgcn_cvt_pkrtz(a, b);
    return __builtin_bit_cast(int, r);
}

// ---------------------------------------------------------------------------
// Prep 1: transpose + split fp32 weight [K][N] -> hi/lo fp16 [N][K]
// ---------------------------------------------------------------------------
__global__ __launch_bounds__(256) void transpose_split_kernel(
    const float* __restrict__ src, int K, int N,
    unsigned short* __restrict__ dh, unsigned short* __restrict__ dl)
{
    __shared__ float T[32][33];
    const int tid = threadIdx.x;
    const int c = tid & 31, r0 = tid >> 5;
    const int nb = blockIdx.x * 32, kb = blockIdx.y * 32;
    #pragma unroll
    for (int i = 0; i < 4; ++i)
        T[r0 + i * 8][c] = src[(size_t)(kb + r0 + i * 8) * N + nb + c];
    __syncthreads();
    #pragma unroll
    for (int i = 0; i < 4; ++i) {
        int n = r0 + i * 8;
        unsigned short hi, lo;
        split_w_f16(T[c][n], hi, lo);
        size_t off = (size_t)(nb + n) * K + kb + c;
        dh[off] = hi;
        dl[off] = lo;
    }
}

// ---------------------------------------------------------------------------
// Prep 2: decay fp32 -> fp16 (post-softmax multiplier; fp16 rel err ~5e-4)
// ---------------------------------------------------------------------------
__global__ __launch_bounds__(256) void decay_to_half_kernel(
    const float* __restrict__ D, unsigned short* __restrict__ D16)
{
    size_t i = ((size_t)blockIdx.x * 256 + threadIdx.x) * 4;
    float4 v = *(const float4*)(D + i);
    ushort4 o;
    o.x = f16_bits(v.x);
    o.y = f16_bits(v.y);
    o.z = f16_bits(v.z);
    o.w = f16_bits(v.w);
    *(ushort4*)(D16 + i) = o;
}

// ---------------------------------------------------------------------------
// Prep 3: X fp32 -> single fp16 (RTN). Xf aliases AOf (dead until attn).
// ---------------------------------------------------------------------------
__global__ __launch_bounds__(256) void x_to_half_kernel(
    const float* __restrict__ X, unsigned short* __restrict__ Xf)
{
    size_t i = ((size_t)blockIdx.x * 256 + threadIdx.x) * 8;
    float4 a = *(const float4*)(X + i);
    float4 b = *(const float4*)(X + i + 4);
    float f[8] = {a.x, a.y, a.z, a.w, b.x, b.y, b.z, b.w};
    short8 o;
    #pragma unroll
    for (int e = 0; e < 8; ++e) o[e] = (short)f16_bits(f[e]);
    *(short8*)(Xf + i) = o;
}

// async global->LDS, 16 bytes per lane; LDS dest = wave-uniform base + lane*16
__device__ __forceinline__ void gload_lds16(const unsigned short* g, unsigned short* l) {
    __builtin_amdgcn_global_load_lds(
        (const __attribute__((address_space(1))) unsigned int*)g,
        (__attribute__((address_space(3))) unsigned int*)l,
        16, 0, 0);
}

// ---------------------------------------------------------------------------
// GEMM1 (fp16, 2-term: Xf * (Wh + Wl)): qkv = x @ W_qkv
// 2-phase double-buffered global_load_lds staging, one barrier per K-step.
// Q epilogue folds SCALE * log2(e); Q/K/V all stored as single fp16.
// ---------------------------------------------------------------------------
__global__ __launch_bounds__(256) void gemm_qkv_mfma(
    const unsigned short* __restrict__ Xf,
    const unsigned short* __restrict__ Wh, const unsigned short* __restrict__ Wl,
    unsigned short* __restrict__ Qf, unsigned short* __restrict__ Kf,
    unsigned short* __restrict__ Vt)
{
    __shared__ union {
        struct { unsigned short Af[2][4096], Bh[2][4096], Bl[2][4096]; } s;
        unsigned short bounce[128][136];   // V-transpose bounce (epilogue only)
    } u;

    const int tid  = threadIdx.x;
    const int w    = tid >> 6;
    const int lane = tid & 63;
    const int quad = lane >> 4;
    const int l16  = lane & 15;
    const int n0 = blockIdx.x * 128;
    const int m0 = blockIdx.y * 128;
    const int wm = w >> 1, wn = w & 1;

    floatx4 acc[4][4];
    #pragma unroll
    for (int im = 0; im < 4; ++im)
        #pragma unroll
        for (int in = 0; in < 4; ++in)
            acc[im][in] = (floatx4){0.f, 0.f, 0.f, 0.f};

    // prologue: stage K-tile 0 into buffer 0
    #pragma unroll
    for (int i = 0; i < 2; ++i) {
        const int row = i * 64 + w * 16 + l16;
        const size_t aoff = (size_t)(m0 + row) * GK + quad * 8;
        const size_t boff = (size_t)(n0 + row) * GK + quad * 8;
        const int lb = (i * 4 + w) * 512;
        gload_lds16(Xf + aoff, &u.s.Af[0][lb]);
        gload_lds16(Wh + boff, &u.s.Bh[0][lb]);
        gload_lds16(Wl + boff, &u.s.Bl[0][lb]);
    }

    int cur = 0;
    for (int k0 = 0; k0 < GK; k0 += 32) {
        __syncthreads();   // vmcnt(0): buf[cur] ready; lgkm: buf[cur^1] free
        if (k0 + 32 < GK) {
            const int kn = k0 + 32;
            #pragma unroll
            for (int i = 0; i < 2; ++i) {
                const int row = i * 64 + w * 16 + l16;
                const size_t aoff = (size_t)(m0 + row) * GK + kn + quad * 8;
                const size_t boff = (size_t)(n0 + row) * GK + kn + quad * 8;
                const int lb = (i * 4 + w) * 512;
                gload_lds16(Xf + aoff, &u.s.Af[cur ^ 1][lb]);
                gload_lds16(Wh + boff, &u.s.Bh[cur ^ 1][lb]);
                gload_lds16(Wl + boff, &u.s.Bl[cur ^ 1][lb]);
            }
        }

        half8 faf[4], fbh[4], fbl[4];
        #pragma unroll
        for (int t = 0; t < 4; ++t) {
            const int ca = ((wm * 4 + t) * 4 + quad) * 16 + l16;
            faf[t] = *(const half8*)&u.s.Af[cur][ca * 8];
            const int cb = ((wn * 4 + t) * 4 + quad) * 16 + l16;
            fbh[t] = *(const half8*)&u.s.Bh[cur][cb * 8];
            fbl[t] = *(const half8*)&u.s.Bl[cur][cb * 8];
        }
        #pragma unroll
        for (int im = 0; im < 4; ++im)
            #pragma unroll
            for (int in = 0; in < 4; ++in) {
                floatx4 a = acc[im][in];
                a = MFMA16(faf[im], fbh[in], a, 0, 0, 0);
                a = MFMA16(faf[im], fbl[in], a, 0, 0, 0);
                acc[im][in] = a;
            }
        cur ^= 1;
    }

    // ---- epilogue ----
    const int which = n0 >> 9;       // 0=q 1=k 2=v (128-tiles never straddle)
    const int b    = m0 >> 10;
    const int tokb = m0 & 1023;
    if (which < 2) {
        unsigned short* OUT = which ? Kf : Qf;
        // Q: fold SCALE * log2(e) = 0.125 * 1.4426950408889634
        const float sc = which ? 1.0f : 0.18033688011112042f;
        #pragma unroll
        for (int im = 0; im < 4; ++im) {
            const int tok = tokb + wm * 64 + im * 16 + quad * 4;
            #pragma unroll
            for (int in = 0; in < 4; ++in) {
                const int ncol = n0 + wn * 64 + in * 16 + l16;
                const int h = (ncol & 511) >> 6, d = ncol & 63;
                const size_t base = ((size_t)(b * Hh + h) * Nn + tok) * DHd + d;
                #pragma unroll
                for (int r = 0; r < 4; ++r)
                    OUT[base + (size_t)r * DHd] = f16_bits(acc[im][in][r] * sc);
            }
        }
    } else {
        // V: fp16 + transpose through LDS bounce -> Vt [bh][64][1024]
        __syncthreads();
        #pragma unroll
        for (int im = 0; im < 4; ++im)
            #pragma unroll
            for (int in = 0; in < 4; ++in)
                #pragma unroll
                for (int r = 0; r < 4; ++r)
                    u.bounce[wm * 64 + im * 16 + quad * 4 + r][wn * 64 + in * 16 + l16] =
                        f16_bits(acc[im][in][r]);
        __syncthreads();
        const int c = tid >> 1, tq = (tid & 1) * 64;
        const int h = ((n0 + c) & 511) >> 6, d = c & 63;
        unsigned short* vbase = Vt + ((size_t)(b * Hh + h) * DHd + d) * Nn + tokb;
        #pragma unroll
        for (int uu = 0; uu < 8; ++uu) {
            short8 v8;
            #pragma unroll
            for (int e = 0; e < 8; ++e)
                v8[e] = (short)u.bounce[tq + uu * 8 + e][c];
            *(short8*)&vbase[tq + uu * 8] = v8;
        }
    }
}

// ---------------------------------------------------------------------------
// MFMA flash attention, all-fp16 operands: XCD-chunked swizzle, swapped QK^T
// (single-term fp16 Q,K: 2 MFMA/nh vs 6 for split-bf16), shuffle-free softmax
// fast path, in-register fp16 P (cvt_pkrtz), pointer-bump prefetch.
// ---------------------------------------------------------------------------
__global__ __launch_bounds__(256) void attn_mfma_kernel(
    const unsigned short* __restrict__ Qf, const unsigned short* __restrict__ Kf,
    const unsigned short* __restrict__ Vt, const unsigned short* __restrict__ D16,
    unsigned short* __restrict__ AOf)
{
    __shared__ unsigned short Kfs[32][72];   // [permuted j][d]
    __shared__ unsigned short Vts[64][40];   // [d][j]

    const int tid  = threadIdx.x;
    const int wave = tid >> 6;
    const int lane = tid & 63;
    const int quad = lane >> 4;
    const int l16  = lane & 15;
    const int lb   = blockIdx.x;
    const int wg   = (lb & 7) * 512 + (lb >> 3);
    const int bh   = wg >> 4;
    const int i0   = (wg & 15) << 6;
    const int b    = bh >> 3, h = bh & 7;
    const int iw   = i0 + wave * 16;

    // Q fragments (MFMA B operand: col = l16 = q-row, k = quad*8+e = d)
    const size_t qoff = ((size_t)bh * Nn + iw + l16) * DHd + quad * 8;
    const half8 qf0 = *(const half8*)(Qf + qoff);
    const half8 qf1 = *(const half8*)(Qf + qoff + 32);

    floatx4 o_acc[4];
    #pragma unroll
    for (int nt = 0; nt < 4; ++nt) o_acc[nt] = (floatx4){0.f, 0.f, 0.f, 0.f};
    float m = -INFINITY;      // per-lane: row q = l16 (replicated across quads)
    float l = 0.f;            // PER-LANE partial denominator; reduced at end

    const int sj  = tid >> 3, sc2 = (tid & 7) * 8;       // K tile: 32 x 64
    const int prow = ((sj >> 2) & 1) * 16 + ((sj >> 3) << 2) + (sj & 3);
    const int vd  = tid >> 2, vj8 = (tid & 3) * 8;       // Vt tile: 64 x 32
    const unsigned short* Dp = D16 + ((size_t)h * Nn + iw + l16) * Nn + quad * 8;

    // pointer-bump staging sources
    const unsigned short* kpf = Kf + (size_t)bh * Nn * DHd + (size_t)sj * DHd + sc2;
    const unsigned short* vpv = Vt + (size_t)bh * DHd * Nn + (size_t)vd * Nn + vj8;

    short8 pk_f = *(const short8*)kpf; kpf += 32 * DHd;
    short8 pk_v = *(const short8*)vpv; vpv += 32;

    for (int j0 = 0; j0 < Nn; j0 += 32) {
        const short8 dc = *(const short8*)(Dp + j0);     // 8 fp16 decay values
        __syncthreads();
        *(short8*)&Kfs[prow][sc2] = pk_f;
        *(short8*)&Vts[vd][vj8]   = pk_v;
        __syncthreads();
        {   // prefetch next tile (overshoot lands in adjacent workspace, discarded)
            pk_f = *(const short8*)kpf; kpf += 32 * DHd;
            pk_v = *(const short8*)vpv; vpv += 32;
        }

        // QK^T swapped: A = K (row = j), B = Q (col = q). Single fp16 terms.
        floatx4 sacc[2];
        #pragma unroll
        for (int nh = 0; nh < 2; ++nh) {
            const int kr = nh * 16 + l16;
            half8 kf0 = *(const half8*)&Kfs[kr][quad * 8];
            half8 kf1 = *(const half8*)&Kfs[kr][32 + quad * 8];
            floatx4 a = (floatx4){0.f, 0.f, 0.f, 0.f};
            a = MFMA16(kf0, qf0, a, 0, 0, 0);
            a = MFMA16(kf1, qf1, a, 0, 0, 0);
            sacc[nh] = a;
        }
        // lane holds S[q=l16][j0 + quad*8 + nh*4 + r]  (log2 domain)

        // lane-local max over this lane's 8 values (no cross-lane in fast path)
        float t = fmaxf(fmaxf(fmaxf(sacc[0][0], sacc[0][1]), fmaxf(sacc[0][2], sacc[0][3])),
                        fmaxf(fmaxf(sacc[1][0], sacc[1][1]), fmaxf(sacc[1][2], sacc[1][3])));

        // T13 defer-max: __all over per-lane maxima == test on full row max
        if (!__all(t <= m + 8.0f)) {
            t = fmaxf(t, __shfl_xor(t, 16));
            t = fmaxf(t, __shfl_xor(t, 32));
            const float nm = fmaxf(m, t);
            const float fac = EXP2(m - nm);
            m = nm;
            l *= fac;
            float fr[4];
            #pragma unroll
            for (int r = 0; r < 4; ++r) fr[r] = __shfl(fac, quad * 4 + r);
            #pragma unroll
            for (int nt = 0; nt < 4; ++nt) {
                floatx4 t4 = o_acc[nt];
                t4[0] *= fr[0]; t4[1] *= fr[1]; t4[2] *= fr[2]; t4[3] *= fr[3];
                o_acc[nt] = t4;
            }
        }

        float p[8];
        #pragma unroll
        for (int e = 0; e < 4; ++e) p[e]     = EXP2(sacc[0][e] - m);
        #pragma unroll
        for (int e = 0; e < 4; ++e) p[4 + e] = EXP2(sacc[1][e] - m);
        l += ((p[0] + p[1]) + (p[2] + p[3])) + ((p[4] + p[5]) + (p[6] + p[7]));

        // P * decay -> fp16 A-fragment, fully in-register (cvt_pkrtz)
        union { int i4[4]; half8 v8; } pfu;
        #pragma unroll
        for (int e = 0; e < 4; ++e) {
            const float d0 = __half2float(__ushort_as_half((unsigned short)dc[2 * e]));
            const float d1 = __half2float(__ushort_as_half((unsigned short)dc[2 * e + 1]));
            pfu.i4[e] = cvt_pk_f16(p[2 * e] * d0, p[2 * e + 1] * d1);
        }
        #pragma unroll
        for (int nt = 0; nt < 4; ++nt) {
            half8 vf = *(const half8*)&Vts[nt * 16 + l16][quad * 8];
            o_acc[nt] = MFMA16(pfu.v8, vf, o_acc[nt], 0, 0, 0);
        }
    }

    // reduce the per-lane partial denominator across quads (once)
    float lsum = l;
    lsum += __shfl_xor(lsum, 16);
    lsum += __shfl_xor(lsum, 32);
    const float inv = 1.f / lsum;
    float ir[4];
    #pragma unroll
    for (int r = 0; r < 4; ++r) ir[r] = __shfl(inv, quad * 4 + r);
    const size_t aob = ((size_t)b * Nn + i0 + wave * 16) * DIMc + h * DHd;
    #pragma unroll
    for (int nt = 0; nt < 4; ++nt)
        #pragma unroll
        for (int r = 0; r < 4; ++r) {
            const size_t off = aob + (size_t)(quad * 4 + r) * DIMc + nt * 16 + l16;
            AOf[off] = f16_bits(o_acc[nt][r] * ir[r]);
        }
}

// ---------------------------------------------------------------------------
// GEMM2 (fp16, 2-term: AOf * (Wh + Wl)): out = AO @ W_out + b_out
// 2-phase double-buffered global_load_lds staging.
// ---------------------------------------------------------------------------
__global__ __launch_bounds__(256) void gemm_out_mfma(
    const unsigned short* __restrict__ Af,
    const unsigned short* __restrict__ Wh, const unsigned short* __restrict__ Wl,
    const float* __restrict__ bias, float* __restrict__ C)
{
    __shared__ struct { unsigned short Aa[2][4096], Bh[2][4096], Bl[2][4096]; } s;

    const int tid  = threadIdx.x;
    const int w    = tid >> 6;
    const int lane = tid & 63;
    const int quad = lane >> 4;
    const int l16  = lane & 15;
    const int n0 = blockIdx.x * 128;
    const int m0 = blockIdx.y * 128;
    const int wm = w >> 1, wn = w & 1;

    floatx4 acc[4][4];
    #pragma unroll
    for (int im = 0; im < 4; ++im)
        #pragma unroll
        for (int in = 0; in < 4; ++in)
            acc[im][in] = (floatx4){0.f, 0.f, 0.f, 0.f};

    #pragma unroll
    for (int i = 0; i < 2; ++i) {
        const int row = i * 64 + w * 16 + l16;
        const size_t aoff = (size_t)(m0 + row) * GK + quad * 8;
        const size_t boff = (size_t)(n0 + row) * GK + quad * 8;
        const int lb = (i * 4 + w) * 512;
        gload_lds16(Af + aoff, &s.Aa[0][lb]);
        gload_lds16(Wh + boff, &s.Bh[0][lb]);
        gload_lds16(Wl + boff, &s.Bl[0][lb]);
    }

    int cur = 0;
    for (int k0 = 0; k0 < GK; k0 += 32) {
        __syncthreads();
        if (k0 + 32 < GK) {
            const int kn = k0 + 32;
            #pragma unroll
            for (int i = 0; i < 2; ++i) {
                const int row = i * 64 + w * 16 + l16;
                const size_t aoff = (size_t)(m0 + row) * GK + kn + quad * 8;
                const size_t boff = (size_t)(n0 + row) * GK + kn + quad * 8;
                const int lb = (i * 4 + w) * 512;
                gload_lds16(Af + aoff, &s.Aa[cur ^ 1][lb]);
                gload_lds16(Wh + boff, &s.Bh[cur ^ 1][lb]);
                gload_lds16(Wl + boff, &s.Bl[cur ^ 1][lb]);
            }
        }

        half8 faf[4], fbh[4], fbl[4];
        #pragma unroll
        for (int t = 0; t < 4; ++t) {
            const int ca = ((wm * 4 + t) * 4 + quad) * 16 + l16;
            faf[t] = *(const half8*)&s.Aa[cur][ca * 8];
            const int cb = ((wn * 4 + t) * 4 + quad) * 16 + l16;
            fbh[t] = *(const half8*)&s.Bh[cur][cb * 8];
            fbl[t] = *(const half8*)&s.Bl[cur][cb * 8];
        }
        #pragma unroll
        for (int im = 0; im < 4; ++im)
            #pragma unroll
            for (int in = 0; in < 4; ++in) {
                floatx4 a = acc[im][in];
                a = MFMA16(faf[im], fbh[in], a, 0, 0, 0);
                a = MFMA16(faf[im], fbl[in], a, 0, 0, 0);
                acc[im][in] = a;
            }
        cur ^= 1;
    }

    float biasv[4];
    #pragma unroll
    for (int in = 0; in < 4; ++in) biasv[in] = bias[n0 + wn * 64 + in * 16 + l16];
    #pragma unroll
    for (int im = 0; im < 4; ++im)
        #pragma unroll
        for (int in = 0; in < 4; ++in) {
            const int mrow = m0 + wm * 64 + im * 16 + quad * 4;
            const int ncol = n0 + wn * 64 + in * 16 + l16;
            #pragma unroll
            for (int r = 0; r < 4; ++r)
                C[(size_t)(mrow + r) * DIMc + ncol] = acc[im][in][r] + biasv[in];
        }
}

// ---------------------------------------------------------------------------
extern "C" void kernel_launch(void* const* d_in, const int* in_sizes, int n_in,
                              void* d_out, int out_size, void* d_ws, size_t ws_size,
                              hipStream_t stream)
{
    const float* x     = (const float*)d_in[0];
    const float* Wqkv  = (const float*)d_in[1];
    const float* Wout  = (const float*)d_in[2];
    const float* bout  = (const float*)d_in[3];
    const float* decay = (const float*)d_in[4];

    const size_t E = (size_t)32768 * 512;   // 16,777,216
    unsigned short* p = (unsigned short*)d_ws;
    unsigned short* Qf  = p; p += E;
    unsigned short* Kf  = p; p += E;        // attn prefetch overshoot -> Vt (ok)
    unsigned short* Vt  = p; p += E;        // attn prefetch overshoot -> AOf (ok)
    unsigned short* AOf = p; p += E;
    unsigned short* Wqh = p; p += 786432;
    unsigned short* Wql = p; p += 786432;
    unsigned short* Woh = p; p += 262144;
    unsigned short* Wol = p; p += 262144;
    unsigned short* D16 = p;               // 8,388,608 halves
    // total: ~155 MiB. Xf ALIASES AOf: X's fp16 copy is dead before attn
    // writes AO (stream-serialized), so no extra workspace.
    unsigned short* Xf = AOf;

    transpose_split_kernel<<<dim3(48, 16), 256, 0, stream>>>(Wqkv, 512, 1536, Wqh, Wql);
    transpose_split_kernel<<<dim3(16, 16), 256, 0, stream>>>(Wout, 512, 512, Woh, Wol);
    decay_to_half_kernel<<<dim3(8192), 256, 0, stream>>>(decay, D16);
    x_to_half_kernel<<<dim3(8192), 256, 0, stream>>>(x, Xf);
    gemm_qkv_mfma<<<dim3(12, 256), 256, 0, stream>>>(Xf, Wqh, Wql, Qf, Kf, Vt);
    attn_mfma_kernel<<<dim3(4096), 256, 0, stream>>>(Qf, Kf, Vt, D16, AOf);
    gemm_out_mfma<<<dim3(4, 256), 256, 0, stream>>>(AOf, Woh, Wol, bout, (float*)d_out);
}